// Round 1
// baseline (832.373 us; speedup 1.0000x reference)
//
#include <hip/hip_runtime.h>

#ifndef F1
#define F1 64
#define F2 32
#endif

// ---------------- CSR build ----------------

__global__ __launch_bounds__(256) void hist_kernel(const int* __restrict__ dst,
                                                   int* __restrict__ deg, int E) {
    int e = blockIdx.x * 256 + threadIdx.x;
    if (e < E) atomicAdd(&deg[dst[e]], 1);
}

__global__ __launch_bounds__(256) void dinv_kernel(const int* __restrict__ deg,
                                                   float* __restrict__ dinv, int n) {
    int i = blockIdx.x * 256 + threadIdx.x;
    if (i < n) dinv[i] = rsqrtf((float)(deg[i] + 1));  // +1 self loop
}

// exclusive scan of deg -> row_off. 1024 elems/block (256 thr x 4).
__global__ __launch_bounds__(256) void scan_blocks_kernel(const int* __restrict__ deg,
                                                          int* __restrict__ tmp,
                                                          int* __restrict__ blk_sums, int n) {
    __shared__ int sdata[256];
    int t = threadIdx.x;
    int base = blockIdx.x * 1024 + t * 4;
    int v[4];
#pragma unroll
    for (int j = 0; j < 4; ++j) v[j] = (base + j < n) ? deg[base + j] : 0;
    int mysum = v[0] + v[1] + v[2] + v[3];
    sdata[t] = mysum;
    __syncthreads();
    for (int ofs = 1; ofs < 256; ofs <<= 1) {
        int val = (t >= ofs) ? sdata[t - ofs] : 0;
        __syncthreads();
        sdata[t] += val;
        __syncthreads();
    }
    int incl = sdata[t];
    int excl = incl - mysum;
    if (t == 255) blk_sums[blockIdx.x] = incl;
    int run = excl;
#pragma unroll
    for (int j = 0; j < 4; ++j) {
        if (base + j < n) tmp[base + j] = run;
        run += v[j];
    }
}

__global__ __launch_bounds__(128) void scan_sums_kernel(const int* __restrict__ blk_sums,
                                                        int* __restrict__ blk_scanned, int nb) {
    __shared__ int sdata[128];
    int t = threadIdx.x;
    int mine = (t < nb) ? blk_sums[t] : 0;
    sdata[t] = mine;
    __syncthreads();
    for (int ofs = 1; ofs < 128; ofs <<= 1) {
        int val = (t >= ofs) ? sdata[t - ofs] : 0;
        __syncthreads();
        sdata[t] += val;
        __syncthreads();
    }
    blk_scanned[t] = sdata[t] - mine;  // exclusive
}

__global__ __launch_bounds__(256) void scan_add_kernel(const int* __restrict__ tmp,
                                                       const int* __restrict__ blk_scanned,
                                                       int* __restrict__ row_off, int n) {
    int i = blockIdx.x * 256 + threadIdx.x;
    if (i < n) row_off[i] = tmp[i] + blk_scanned[i >> 10];
}

__global__ __launch_bounds__(256) void fill_kernel(const int* __restrict__ src,
                                                   const int* __restrict__ dst,
                                                   const int* __restrict__ row_off,
                                                   int* __restrict__ cursor,
                                                   int* __restrict__ csr, int E) {
    int e = blockIdx.x * 256 + threadIdx.x;
    if (e < E) {
        int d = dst[e];
        int pos = row_off[d] + atomicAdd(&cursor[d], 1);
        csr[pos] = src[e];
    }
}

// ---------------- GEMM (f32 vector ALU), C = (A @ B) * dinv[row] ----------------
// threads = (BM/TM)*(BN/TN) = 256. A: [M,K] row-major, B: [K,N] row-major.

template <int BM, int BN, int BK, int TM, int TN>
__global__ __launch_bounds__(256) void gemm_scale_kernel(const float* __restrict__ A,
                                                         const float* __restrict__ B,
                                                         const float* __restrict__ dinv,
                                                         float* __restrict__ C,
                                                         int M, int K, int N) {
    constexpr int TX = BN / TN;  // 16
    constexpr int TY = BM / TM;  // 16
    __shared__ float As_t[BK][BM + 4];  // transposed A tile, padded (keeps 16B align)
    __shared__ float Bs[BK][BN + 4];

    int tid = threadIdx.x;
    int tx = tid % TX, ty = tid / TX;
    int row0 = blockIdx.x * BM;

    float acc[TM][TN];
#pragma unroll
    for (int j = 0; j < TM; ++j)
#pragma unroll
        for (int i = 0; i < TN; ++i) acc[j][i] = 0.f;

    for (int k0 = 0; k0 < K; k0 += BK) {
        // A tile: BM*BK floats, float4 loads, transposed store
        constexpr int V4A = BM * BK / 4;
#pragma unroll
        for (int i = tid; i < V4A; i += 256) {
            int flat = i * 4;
            int r = flat / BK, c = flat % BK;
            int gr = row0 + r;
            float4 val = make_float4(0.f, 0.f, 0.f, 0.f);
            if (gr < M) val = *reinterpret_cast<const float4*>(&A[(size_t)gr * K + k0 + c]);
            As_t[c + 0][r] = val.x;
            As_t[c + 1][r] = val.y;
            As_t[c + 2][r] = val.z;
            As_t[c + 3][r] = val.w;
        }
        // B tile: BK*BN floats
        constexpr int V4B = BK * BN / 4;
#pragma unroll
        for (int i = tid; i < V4B; i += 256) {
            int flat = i * 4;
            int r = flat / BN, c = flat % BN;
            float4 val = *reinterpret_cast<const float4*>(&B[(size_t)(k0 + r) * N + c]);
            *reinterpret_cast<float4*>(&Bs[r][c]) = val;
        }
        __syncthreads();

#pragma unroll
        for (int kk = 0; kk < BK; ++kk) {
            float a[TM], b[TN];
#pragma unroll
            for (int j = 0; j < TM; ++j) a[j] = As_t[kk][ty * TM + j];
#pragma unroll
            for (int i = 0; i < TN; ++i) b[i] = Bs[kk][tx * TN + i];
#pragma unroll
            for (int j = 0; j < TM; ++j)
#pragma unroll
                for (int i = 0; i < TN; ++i) acc[j][i] += a[j] * b[i];
        }
        __syncthreads();
    }

#pragma unroll
    for (int j = 0; j < TM; ++j) {
        int gr = row0 + ty * TM + j;
        if (gr < M) {
            float s = dinv[gr];
            if constexpr (TN == 4) {
                float4 o;
                o.x = acc[j][0] * s; o.y = acc[j][1] * s;
                o.z = acc[j][2] * s; o.w = acc[j][3] * s;
                *reinterpret_cast<float4*>(&C[(size_t)gr * N + tx * TN]) = o;
            } else if constexpr (TN == 2) {
                float2 o;
                o.x = acc[j][0] * s; o.y = acc[j][1] * s;
                *reinterpret_cast<float2*>(&C[(size_t)gr * N + tx * TN]) = o;
            } else {
#pragma unroll
                for (int i = 0; i < TN; ++i) C[(size_t)gr * N + tx * TN + i] = acc[j][i] * s;
            }
        }
    }
}

// ---------------- Aggregation layer 1: wave per node, lane = feature (64) ----------------

__global__ __launch_bounds__(256) void agg1_kernel(const float* __restrict__ g1,
                                                   const int* __restrict__ row_off,
                                                   const int* __restrict__ deg,
                                                   const int* __restrict__ csr,
                                                   const float* __restrict__ dinv,
                                                   const float* __restrict__ b1,
                                                   float* __restrict__ h1, int n) {
    int node = (blockIdx.x * 256 + threadIdx.x) >> 6;
    int lane = threadIdx.x & 63;
    if (node >= n) return;
    int start = row_off[node];
    int cnt = deg[node];
    int end = start + cnt;
    float acc = g1[(size_t)node * F1 + lane];  // self loop
    int e = start;
    for (; e + 4 <= end; e += 4) {
        int s0 = csr[e], s1 = csr[e + 1], s2 = csr[e + 2], s3 = csr[e + 3];
        float v0 = g1[(size_t)s0 * F1 + lane];
        float v1 = g1[(size_t)s1 * F1 + lane];
        float v2 = g1[(size_t)s2 * F1 + lane];
        float v3 = g1[(size_t)s3 * F1 + lane];
        acc += v0; acc += v1; acc += v2; acc += v3;
    }
    for (; e < end; ++e) acc += g1[(size_t)csr[e] * F1 + lane];
    float out = acc * dinv[node] + b1[lane];
    h1[(size_t)node * F1 + lane] = fmaxf(out, 0.f);
}

// ---------------- Aggregation layer 2 + fused pooling: half-wave per node (32 feats) ----------------

__global__ __launch_bounds__(256) void agg2_pool_kernel(const float* __restrict__ g2,
                                                        const int* __restrict__ row_off,
                                                        const int* __restrict__ deg,
                                                        const int* __restrict__ csr,
                                                        const float* __restrict__ dinv,
                                                        const float* __restrict__ b2,
                                                        double* __restrict__ pooled, int n) {
    int node = (blockIdx.x * 256 + threadIdx.x) >> 5;
    int lane = threadIdx.x & 31;
    float out = 0.f;
    if (node < n) {
        int start = row_off[node];
        int cnt = deg[node];
        int end = start + cnt;
        float acc = g2[(size_t)node * F2 + lane];  // self loop
        int e = start;
        for (; e + 4 <= end; e += 4) {
            int s0 = csr[e], s1 = csr[e + 1], s2 = csr[e + 2], s3 = csr[e + 3];
            float v0 = g2[(size_t)s0 * F2 + lane];
            float v1 = g2[(size_t)s1 * F2 + lane];
            float v2 = g2[(size_t)s2 * F2 + lane];
            float v3 = g2[(size_t)s3 * F2 + lane];
            acc += v0; acc += v1; acc += v2; acc += v3;
        }
        for (; e < end; ++e) acc += g2[(size_t)csr[e] * F2 + lane];
        out = fmaxf(acc * dinv[node] + b2[lane], 0.f);
    }
    // block: 256 threads = 8 nodes x 32 feats; reduce per feature then one f64 atomic
    __shared__ float sdata[256];
    sdata[threadIdx.x] = out;
    __syncthreads();
    if (threadIdx.x < 32) {
        float s = 0.f;
#pragma unroll
        for (int i = 0; i < 8; ++i) s += sdata[threadIdx.x + i * 32];
        unsafeAtomicAdd(&pooled[threadIdx.x], (double)s);
    }
}

__global__ __launch_bounds__(64) void final_kernel(const double* __restrict__ pooled,
                                                   const float* __restrict__ fcw,
                                                   const float* __restrict__ fcb,
                                                   float* __restrict__ out, int n) {
    if (threadIdx.x == 0) {
        double s = 0.0;
        for (int j = 0; j < F2; ++j) s += (pooled[j] / (double)n) * (double)fcw[j];
        out[0] = (float)(s + (double)fcb[0]);
    }
}

// ---------------- launch ----------------

extern "C" void kernel_launch(void* const* d_in, const int* in_sizes, int n_in,
                              void* d_out, int out_size, void* d_ws, size_t ws_size,
                              hipStream_t stream) {
    const float* x   = (const float*)d_in[0];
    const int*   ei  = (const int*)d_in[1];
    const float* W1  = (const float*)d_in[2];
    const float* b1  = (const float*)d_in[3];
    const float* W2  = (const float*)d_in[4];
    const float* b2  = (const float*)d_in[5];
    const float* fcw = (const float*)d_in[6];
    const float* fcb = (const float*)d_in[7];
    float* out = (float*)d_out;

    const int N = in_sizes[0] / 256;  // 100000
    const int E = in_sizes[1] / 2;    // 3200000
    const int K1 = in_sizes[2] / F1;  // 256
    const int* src = ei;
    const int* dst = ei + E;

    char* ws = (char*)d_ws;
    size_t off = 0;
    auto alloc = [&](size_t bytes) -> void* {
        void* p = ws + off;
        off = (off + bytes + 255) & ~(size_t)255;
        return p;
    };
    int*    deg     = (int*)alloc((size_t)N * 4);
    int*    tmp     = (int*)alloc((size_t)N * 4);
    int*    bsums   = (int*)alloc(512);
    int*    bscan   = (int*)alloc(512);
    int*    row_off = (int*)alloc((size_t)N * 4);
    int*    cursor  = (int*)alloc((size_t)N * 4);
    int*    csr     = (int*)alloc((size_t)E * 4);
    float*  dinv    = (float*)alloc((size_t)N * 4);
    float*  g1      = (float*)alloc((size_t)N * F1 * 4);
    float*  h1      = (float*)alloc((size_t)N * F1 * 4);
    float*  g2      = (float*)alloc((size_t)N * F2 * 4);
    double* pooled  = (double*)alloc(F2 * 8);

    hipMemsetAsync(deg, 0, (size_t)N * 4, stream);
    hipMemsetAsync(cursor, 0, (size_t)N * 4, stream);
    hipMemsetAsync(pooled, 0, F2 * 8, stream);

    int nbE = (E + 255) / 256;
    int nbN = (N + 255) / 256;
    int nbScan = (N + 1023) / 1024;  // 98 <= 128

    hist_kernel<<<nbE, 256, 0, stream>>>(dst, deg, E);
    dinv_kernel<<<nbN, 256, 0, stream>>>(deg, dinv, N);
    scan_blocks_kernel<<<nbScan, 256, 0, stream>>>(deg, tmp, bsums, N);
    scan_sums_kernel<<<1, 128, 0, stream>>>(bsums, bscan, nbScan);
    scan_add_kernel<<<nbN, 256, 0, stream>>>(tmp, bscan, row_off, N);
    fill_kernel<<<nbE, 256, 0, stream>>>(src, dst, row_off, cursor, csr, E);

    // layer 1: g1 = (x @ W1) * dinv
    gemm_scale_kernel<64, 64, 32, 4, 4><<<(N + 63) / 64, 256, 0, stream>>>(x, W1, dinv, g1, N, K1, F1);
    agg1_kernel<<<(N + 3) / 4, 256, 0, stream>>>(g1, row_off, deg, csr, dinv, b1, h1, N);

    // layer 2: g2 = (h1 @ W2) * dinv
    gemm_scale_kernel<64, 32, 32, 4, 2><<<(N + 63) / 64, 256, 0, stream>>>(h1, W2, dinv, g2, N, F1, F2);
    agg2_pool_kernel<<<(N + 7) / 8, 256, 0, stream>>>(g2, row_off, deg, csr, dinv, b2, pooled, N);

    final_kernel<<<1, 64, 0, stream>>>(pooled, fcw, fcb, out, N);
}

// Round 2
// 569.448 us; speedup vs baseline: 1.4617x; 1.4617x over previous
//
#include <hip/hip_runtime.h>

#ifndef F1
#define F1 64
#define F2 32
#endif

// ---------------- CSR build ----------------

__global__ __launch_bounds__(256) void hist_kernel(const int* __restrict__ dst,
                                                   int* __restrict__ deg, int E) {
    int e = blockIdx.x * 256 + threadIdx.x;
    if (e < E) atomicAdd(&deg[dst[e]], 1);
}

__global__ __launch_bounds__(256) void dinv_kernel(const int* __restrict__ deg,
                                                   float* __restrict__ dinv, int n) {
    int i = blockIdx.x * 256 + threadIdx.x;
    if (i < n) dinv[i] = rsqrtf((float)(deg[i] + 1));  // +1 self loop
}

// exclusive scan of deg -> row_off. 1024 elems/block (256 thr x 4).
__global__ __launch_bounds__(256) void scan_blocks_kernel(const int* __restrict__ deg,
                                                          int* __restrict__ tmp,
                                                          int* __restrict__ blk_sums, int n) {
    __shared__ int sdata[256];
    int t = threadIdx.x;
    int base = blockIdx.x * 1024 + t * 4;
    int v[4];
#pragma unroll
    for (int j = 0; j < 4; ++j) v[j] = (base + j < n) ? deg[base + j] : 0;
    int mysum = v[0] + v[1] + v[2] + v[3];
    sdata[t] = mysum;
    __syncthreads();
    for (int ofs = 1; ofs < 256; ofs <<= 1) {
        int val = (t >= ofs) ? sdata[t - ofs] : 0;
        __syncthreads();
        sdata[t] += val;
        __syncthreads();
    }
    int incl = sdata[t];
    int excl = incl - mysum;
    if (t == 255) blk_sums[blockIdx.x] = incl;
    int run = excl;
#pragma unroll
    for (int j = 0; j < 4; ++j) {
        if (base + j < n) tmp[base + j] = run;
        run += v[j];
    }
}

__global__ __launch_bounds__(128) void scan_sums_kernel(const int* __restrict__ blk_sums,
                                                        int* __restrict__ blk_scanned, int nb) {
    __shared__ int sdata[128];
    int t = threadIdx.x;
    int mine = (t < nb) ? blk_sums[t] : 0;
    sdata[t] = mine;
    __syncthreads();
    for (int ofs = 1; ofs < 128; ofs <<= 1) {
        int val = (t >= ofs) ? sdata[t - ofs] : 0;
        __syncthreads();
        sdata[t] += val;
        __syncthreads();
    }
    blk_scanned[t] = sdata[t] - mine;  // exclusive
}

__global__ __launch_bounds__(256) void scan_add_kernel(const int* __restrict__ tmp,
                                                       const int* __restrict__ blk_scanned,
                                                       int* __restrict__ row_off, int n) {
    int i = blockIdx.x * 256 + threadIdx.x;
    if (i < n) row_off[i] = tmp[i] + blk_scanned[i >> 10];
}

__global__ __launch_bounds__(256) void fill_kernel(const int* __restrict__ src,
                                                   const int* __restrict__ dst,
                                                   const int* __restrict__ row_off,
                                                   int* __restrict__ cursor,
                                                   int* __restrict__ csr, int E) {
    int e = blockIdx.x * 256 + threadIdx.x;
    if (e < E) {
        int d = dst[e];
        int pos = row_off[d] + atomicAdd(&cursor[d], 1);
        csr[pos] = src[e];
    }
}

// ---------------- GEMM (f32 vector ALU), C = (A @ B) * dinv[row] ----------------
// threads = (BM/TM)*(BN/TN) = 256. A: [M,K] row-major, B: [K,N] row-major.

template <int BM, int BN, int BK, int TM, int TN>
__global__ __launch_bounds__(256) void gemm_scale_kernel(const float* __restrict__ A,
                                                         const float* __restrict__ B,
                                                         const float* __restrict__ dinv,
                                                         float* __restrict__ C,
                                                         int M, int K, int N) {
    constexpr int TX = BN / TN;
    __shared__ float As_t[BK][BM + 4];  // transposed A tile, padded
    __shared__ float Bs[BK][BN + 4];

    int tid = threadIdx.x;
    int tx = tid % TX, ty = tid / TX;
    int row0 = blockIdx.x * BM;

    float acc[TM][TN];
#pragma unroll
    for (int j = 0; j < TM; ++j)
#pragma unroll
        for (int i = 0; i < TN; ++i) acc[j][i] = 0.f;

    for (int k0 = 0; k0 < K; k0 += BK) {
        // A tile: BM*BK floats, float4 loads, transposed store
        constexpr int V4A = BM * BK / 4;
#pragma unroll
        for (int i = tid; i < V4A; i += 256) {
            int flat = i * 4;
            int r = flat / BK, c = flat % BK;
            int gr = row0 + r;
            float4 val = make_float4(0.f, 0.f, 0.f, 0.f);
            if (gr < M) val = *reinterpret_cast<const float4*>(&A[(size_t)gr * K + k0 + c]);
            As_t[c + 0][r] = val.x;
            As_t[c + 1][r] = val.y;
            As_t[c + 2][r] = val.z;
            As_t[c + 3][r] = val.w;
        }
        // B tile: BK*BN floats
        constexpr int V4B = BK * BN / 4;
#pragma unroll
        for (int i = tid; i < V4B; i += 256) {
            int flat = i * 4;
            int r = flat / BN, c = flat % BN;
            float4 val = *reinterpret_cast<const float4*>(&B[(size_t)(k0 + r) * N + c]);
            *reinterpret_cast<float4*>(&Bs[r][c]) = val;
        }
        __syncthreads();

#pragma unroll
        for (int kk = 0; kk < BK; ++kk) {
            float a[TM], b[TN];
#pragma unroll
            for (int j = 0; j < TM; ++j) a[j] = As_t[kk][ty * TM + j];
#pragma unroll
            for (int i = 0; i < TN; ++i) b[i] = Bs[kk][tx * TN + i];
#pragma unroll
            for (int j = 0; j < TM; ++j)
#pragma unroll
                for (int i = 0; i < TN; ++i) acc[j][i] += a[j] * b[i];
        }
        __syncthreads();
    }

#pragma unroll
    for (int j = 0; j < TM; ++j) {
        int gr = row0 + ty * TM + j;
        if (gr < M) {
            float s = dinv[gr];
            if constexpr (TN == 4) {
                float4 o;
                o.x = acc[j][0] * s; o.y = acc[j][1] * s;
                o.z = acc[j][2] * s; o.w = acc[j][3] * s;
                *reinterpret_cast<float4*>(&C[(size_t)gr * N + tx * TN]) = o;
            } else if constexpr (TN == 2) {
                float2 o;
                o.x = acc[j][0] * s; o.y = acc[j][1] * s;
                *reinterpret_cast<float2*>(&C[(size_t)gr * N + tx * TN]) = o;
            } else {
#pragma unroll
                for (int i = 0; i < TN; ++i) C[(size_t)gr * N + tx * TN + i] = acc[j][i] * s;
            }
        }
    }
}

// ---------------- Aggregation layer 1: wave per node, lane = feature (64) ----------------

__global__ __launch_bounds__(256) void agg1_kernel(const float* __restrict__ g1,
                                                   const int* __restrict__ row_off,
                                                   const int* __restrict__ deg,
                                                   const int* __restrict__ csr,
                                                   const float* __restrict__ dinv,
                                                   const float* __restrict__ b1,
                                                   float* __restrict__ h1, int n) {
    int node = (blockIdx.x * 256 + threadIdx.x) >> 6;
    int lane = threadIdx.x & 63;
    if (node >= n) return;
    float bias = b1[lane];
    float dn = dinv[node];
    int start = row_off[node];
    int cnt = deg[node];
    int end = start + cnt;
    float acc = g1[(size_t)node * F1 + lane];  // self loop
    int e = start;
    for (; e + 8 <= end; e += 8) {
        int s0 = csr[e],     s1 = csr[e + 1], s2 = csr[e + 2], s3 = csr[e + 3];
        int s4 = csr[e + 4], s5 = csr[e + 5], s6 = csr[e + 6], s7 = csr[e + 7];
        float v0 = g1[(size_t)s0 * F1 + lane];
        float v1 = g1[(size_t)s1 * F1 + lane];
        float v2 = g1[(size_t)s2 * F1 + lane];
        float v3 = g1[(size_t)s3 * F1 + lane];
        float v4 = g1[(size_t)s4 * F1 + lane];
        float v5 = g1[(size_t)s5 * F1 + lane];
        float v6 = g1[(size_t)s6 * F1 + lane];
        float v7 = g1[(size_t)s7 * F1 + lane];
        acc += v0; acc += v1; acc += v2; acc += v3;
        acc += v4; acc += v5; acc += v6; acc += v7;
    }
    for (; e < end; ++e) acc += g1[(size_t)csr[e] * F1 + lane];
    float out = acc * dn + bias;
    h1[(size_t)node * F1 + lane] = fmaxf(out, 0.f);
}

// ---------------- Aggregation layer 2 + per-block partial pooling ----------------
// partials layout: [F2][nblocks] (feature-major) so the reducer reads contiguously.

__global__ __launch_bounds__(256) void agg2_pool_kernel(const float* __restrict__ g2,
                                                        const int* __restrict__ row_off,
                                                        const int* __restrict__ deg,
                                                        const int* __restrict__ csr,
                                                        const float* __restrict__ dinv,
                                                        const float* __restrict__ b2,
                                                        float* __restrict__ partials,
                                                        int nblocks, int n) {
    int node = (blockIdx.x * 256 + threadIdx.x) >> 5;
    int lane = threadIdx.x & 31;
    float out = 0.f;
    if (node < n) {
        int start = row_off[node];
        int cnt = deg[node];
        int end = start + cnt;
        float acc = g2[(size_t)node * F2 + lane];  // self loop
        int e = start;
        for (; e + 8 <= end; e += 8) {
            int s0 = csr[e],     s1 = csr[e + 1], s2 = csr[e + 2], s3 = csr[e + 3];
            int s4 = csr[e + 4], s5 = csr[e + 5], s6 = csr[e + 6], s7 = csr[e + 7];
            float v0 = g2[(size_t)s0 * F2 + lane];
            float v1 = g2[(size_t)s1 * F2 + lane];
            float v2 = g2[(size_t)s2 * F2 + lane];
            float v3 = g2[(size_t)s3 * F2 + lane];
            float v4 = g2[(size_t)s4 * F2 + lane];
            float v5 = g2[(size_t)s5 * F2 + lane];
            float v6 = g2[(size_t)s6 * F2 + lane];
            float v7 = g2[(size_t)s7 * F2 + lane];
            acc += v0; acc += v1; acc += v2; acc += v3;
            acc += v4; acc += v5; acc += v6; acc += v7;
        }
        for (; e < end; ++e) acc += g2[(size_t)csr[e] * F2 + lane];
        out = fmaxf(acc * dinv[node] + b2[lane], 0.f);
    }
    // block: 256 threads = 8 nodes x 32 feats; reduce per feature, write partial
    __shared__ float sdata[256];
    sdata[threadIdx.x] = out;
    __syncthreads();
    if (threadIdx.x < 32) {
        float s = 0.f;
#pragma unroll
        for (int i = 0; i < 8; ++i) s += sdata[threadIdx.x + i * 32];
        partials[threadIdx.x * nblocks + blockIdx.x] = s;
    }
}

// 32 blocks, one per feature; contiguous reads of partials[f][*].
__global__ __launch_bounds__(256) void reduce_pool_kernel(const float* __restrict__ partials,
                                                          int nblocks,
                                                          float* __restrict__ pooled) {
    int f = blockIdx.x;
    const float* col = partials + (size_t)f * nblocks;
    float s = 0.f;
    for (int i = threadIdx.x; i < nblocks; i += 256) s += col[i];
    __shared__ float red[256];
    red[threadIdx.x] = s;
    __syncthreads();
    for (int ofs = 128; ofs > 0; ofs >>= 1) {
        if (threadIdx.x < ofs) red[threadIdx.x] += red[threadIdx.x + ofs];
        __syncthreads();
    }
    if (threadIdx.x == 0) pooled[f] = red[0];
}

__global__ __launch_bounds__(64) void final_kernel(const float* __restrict__ pooled,
                                                   const float* __restrict__ fcw,
                                                   const float* __restrict__ fcb,
                                                   float* __restrict__ out, int n) {
    if (threadIdx.x == 0) {
        double s = 0.0;
        for (int j = 0; j < F2; ++j) s += ((double)pooled[j] / (double)n) * (double)fcw[j];
        out[0] = (float)(s + (double)fcb[0]);
    }
}

// ---------------- launch ----------------

extern "C" void kernel_launch(void* const* d_in, const int* in_sizes, int n_in,
                              void* d_out, int out_size, void* d_ws, size_t ws_size,
                              hipStream_t stream) {
    const float* x   = (const float*)d_in[0];
    const int*   ei  = (const int*)d_in[1];
    const float* W1  = (const float*)d_in[2];
    const float* b1  = (const float*)d_in[3];
    const float* W2  = (const float*)d_in[4];
    const float* b2  = (const float*)d_in[5];
    const float* fcw = (const float*)d_in[6];
    const float* fcb = (const float*)d_in[7];
    float* out = (float*)d_out;

    const int N = in_sizes[0] / 256;  // 100000
    const int E = in_sizes[1] / 2;    // 3200000
    const int K1 = in_sizes[2] / F1;  // 256
    const int* src = ei;
    const int* dst = ei + E;

    const int nb2 = (N + 7) / 8;  // agg2 blocks (8 nodes/block)

    char* ws = (char*)d_ws;
    size_t off = 0;
    auto alloc = [&](size_t bytes) -> void* {
        void* p = ws + off;
        off = (off + bytes + 255) & ~(size_t)255;
        return p;
    };
    int*    deg      = (int*)alloc((size_t)N * 4);
    int*    tmp      = (int*)alloc((size_t)N * 4);
    int*    bsums    = (int*)alloc(512);
    int*    bscan    = (int*)alloc(512);
    int*    row_off  = (int*)alloc((size_t)N * 4);
    int*    cursor   = (int*)alloc((size_t)N * 4);
    int*    csr      = (int*)alloc((size_t)E * 4);
    float*  dinv     = (float*)alloc((size_t)N * 4);
    float*  g1       = (float*)alloc((size_t)N * F1 * 4);
    float*  h1       = (float*)alloc((size_t)N * F1 * 4);
    float*  g2       = (float*)alloc((size_t)N * F2 * 4);
    float*  partials = (float*)alloc((size_t)F2 * nb2 * 4);
    float*  pooled   = (float*)alloc(F2 * 4);

    hipMemsetAsync(deg, 0, (size_t)N * 4, stream);
    hipMemsetAsync(cursor, 0, (size_t)N * 4, stream);

    int nbE = (E + 255) / 256;
    int nbN = (N + 255) / 256;
    int nbScan = (N + 1023) / 1024;  // 98 <= 128

    hist_kernel<<<nbE, 256, 0, stream>>>(dst, deg, E);
    dinv_kernel<<<nbN, 256, 0, stream>>>(deg, dinv, N);
    scan_blocks_kernel<<<nbScan, 256, 0, stream>>>(deg, tmp, bsums, N);
    scan_sums_kernel<<<1, 128, 0, stream>>>(bsums, bscan, nbScan);
    scan_add_kernel<<<nbN, 256, 0, stream>>>(tmp, bscan, row_off, N);
    fill_kernel<<<nbE, 256, 0, stream>>>(src, dst, row_off, cursor, csr, E);

    // layer 1: g1 = (x @ W1) * dinv
    gemm_scale_kernel<128, 64, 32, 8, 4><<<(N + 127) / 128, 256, 0, stream>>>(x, W1, dinv, g1, N, K1, F1);
    agg1_kernel<<<(N + 3) / 4, 256, 0, stream>>>(g1, row_off, deg, csr, dinv, b1, h1, N);

    // layer 2: g2 = (h1 @ W2) * dinv
    gemm_scale_kernel<128, 32, 32, 8, 2><<<(N + 127) / 128, 256, 0, stream>>>(h1, W2, dinv, g2, N, F1, F2);
    agg2_pool_kernel<<<nb2, 256, 0, stream>>>(g2, row_off, deg, csr, dinv, b2, partials, nb2, N);

    reduce_pool_kernel<<<F2, 256, 0, stream>>>(partials, nb2, pooled);
    final_kernel<<<1, 64, 0, stream>>>(pooled, fcw, fcb, out, N);
}

// Round 3
// 357.111 us; speedup vs baseline: 2.3309x; 1.5946x over previous
//
#include <hip/hip_runtime.h>

#ifndef F1
#define F1 64
#define F2 32
#endif

#define NBLK 512     // blocks for bucket hist/scatter passes
#define BSH  7       // bucket = dst >> 7  (128 nodes per bucket)
#define BNODES 128

// ---------------- scans (generic) ----------------
// exclusive scan, 1024 elems/block (256 thr x 4).
__global__ __launch_bounds__(256) void scan_blocks_kernel(const int* __restrict__ in,
                                                          int* __restrict__ tmp,
                                                          int* __restrict__ blk_sums, int n) {
    __shared__ int sdata[256];
    int t = threadIdx.x;
    int base = blockIdx.x * 1024 + t * 4;
    int v[4];
#pragma unroll
    for (int j = 0; j < 4; ++j) v[j] = (base + j < n) ? in[base + j] : 0;
    int mysum = v[0] + v[1] + v[2] + v[3];
    sdata[t] = mysum;
    __syncthreads();
    for (int ofs = 1; ofs < 256; ofs <<= 1) {
        int val = (t >= ofs) ? sdata[t - ofs] : 0;
        __syncthreads();
        sdata[t] += val;
        __syncthreads();
    }
    int incl = sdata[t];
    int excl = incl - mysum;
    if (t == 255) blk_sums[blockIdx.x] = incl;
    int run = excl;
#pragma unroll
    for (int j = 0; j < 4; ++j) {
        if (base + j < n) tmp[base + j] = run;
        run += v[j];
    }
}

__global__ __launch_bounds__(512) void scan_sums_kernel(const int* __restrict__ blk_sums,
                                                        int* __restrict__ blk_scanned, int nb) {
    __shared__ int sdata[512];
    int t = threadIdx.x;
    int mine = (t < nb) ? blk_sums[t] : 0;
    sdata[t] = mine;
    __syncthreads();
    for (int ofs = 1; ofs < 512; ofs <<= 1) {
        int val = (t >= ofs) ? sdata[t - ofs] : 0;
        __syncthreads();
        sdata[t] += val;
        __syncthreads();
    }
    blk_scanned[t] = sdata[t] - mine;  // exclusive
}

__global__ __launch_bounds__(256) void scan_add_kernel(const int* __restrict__ tmp,
                                                       const int* __restrict__ blk_scanned,
                                                       int* __restrict__ out, int n) {
    int i = blockIdx.x * 256 + threadIdx.x;
    if (i < n) out[i] = tmp[i] + blk_scanned[i >> 10];
}

// ---------------- bucket passes (counting sort by dst>>BSH) ----------------

// Per-block histogram of bucket keys, written transposed: hist_T[k*NBLK + b].
__global__ __launch_bounds__(256) void bucket_hist_kernel(const int* __restrict__ dst,
                                                          int* __restrict__ hist_T,
                                                          int E, int CH, int NB) {
    __shared__ int lh[1024];
    int b = blockIdx.x;
    for (int i = threadIdx.x; i < NB; i += 256) lh[i] = 0;
    __syncthreads();
    int start = b * CH, end = min(E, start + CH);
    for (int e = start + threadIdx.x; e < end; e += 256)
        atomicAdd(&lh[dst[e] >> BSH], 1);
    __syncthreads();
    for (int k = threadIdx.x; k < NB; k += 256)
        hist_T[k * NBLK + b] = lh[k];
}

// Scatter (src,dst) pairs into contiguous bucket regions using exact offsets.
__global__ __launch_bounds__(256) void bucket_scatter_kernel(const int* __restrict__ src,
                                                             const int* __restrict__ dst,
                                                             const int* __restrict__ hscan,
                                                             int2* __restrict__ buck,
                                                             int E, int CH, int NB) {
    __shared__ int cur[1024];
    int b = blockIdx.x;
    for (int i = threadIdx.x; i < NB; i += 256) cur[i] = hscan[i * NBLK + b];
    __syncthreads();
    int start = b * CH, end = min(E, start + CH);
    for (int e = start + threadIdx.x; e < end; e += 256) {
        int d = dst[e];
        int pos = atomicAdd(&cur[d >> BSH], 1);
        buck[pos] = make_int2(src[e], d);
    }
}

// Per-bucket degree count + dinv (dense reads/writes, LDS counters only).
__global__ __launch_bounds__(256) void bucket_deg_kernel(const int2* __restrict__ buck,
                                                         const int* __restrict__ hscan,
                                                         int* __restrict__ deg,
                                                         float* __restrict__ dinv,
                                                         int E, int N, int NB) {
    __shared__ int cnt[BNODES];
    int k = blockIdx.x;
    if (threadIdx.x < BNODES) cnt[threadIdx.x] = 0;
    __syncthreads();
    int bs = hscan[k * NBLK];
    int be = (k + 1 < NB) ? hscan[(k + 1) * NBLK] : E;
    for (int e = bs + threadIdx.x; e < be; e += 256)
        atomicAdd(&cnt[buck[e].y & (BNODES - 1)], 1);
    __syncthreads();
    int node0 = k << BSH;
    int i = node0 + threadIdx.x;
    if (threadIdx.x < BNODES && i < N) {
        int c = cnt[threadIdx.x];
        deg[i] = c;
        dinv[i] = rsqrtf((float)(c + 1));  // +1 self loop
    }
}

// Per-bucket CSR fill: all csr writes land in one small L2-hot region per block.
__global__ __launch_bounds__(256) void bucket_fill_kernel(const int2* __restrict__ buck,
                                                          const int* __restrict__ hscan,
                                                          const int* __restrict__ row_off,
                                                          int* __restrict__ csr,
                                                          int E, int N, int NB) {
    __shared__ int lrow[BNODES];
    __shared__ int lcur[BNODES];
    int k = blockIdx.x;
    int node0 = k << BSH;
    if (threadIdx.x < BNODES) {
        lcur[threadIdx.x] = 0;
        int i = node0 + threadIdx.x;
        lrow[threadIdx.x] = (i < N) ? row_off[i] : 0;
    }
    __syncthreads();
    int bs = hscan[k * NBLK];
    int be = (k + 1 < NB) ? hscan[(k + 1) * NBLK] : E;
    for (int e = bs + threadIdx.x; e < be; e += 256) {
        int2 p = buck[e];
        int li = p.y & (BNODES - 1);
        int pos = lrow[li] + atomicAdd(&lcur[li], 1);
        csr[pos] = p.x;
    }
}

// ---------------- GEMM (f32 vector ALU), C = (A @ B) * dinv[row] ----------------

template <int BM, int BN, int BK, int TM, int TN>
__global__ __launch_bounds__(256) void gemm_scale_kernel(const float* __restrict__ A,
                                                         const float* __restrict__ B,
                                                         const float* __restrict__ dinv,
                                                         float* __restrict__ C,
                                                         int M, int K, int N) {
    constexpr int TX = BN / TN;
    __shared__ float As_t[BK][BM + 4];  // transposed A tile, padded
    __shared__ float Bs[BK][BN + 4];

    int tid = threadIdx.x;
    int tx = tid % TX, ty = tid / TX;
    int row0 = blockIdx.x * BM;

    float acc[TM][TN];
#pragma unroll
    for (int j = 0; j < TM; ++j)
#pragma unroll
        for (int i = 0; i < TN; ++i) acc[j][i] = 0.f;

    for (int k0 = 0; k0 < K; k0 += BK) {
        constexpr int V4A = BM * BK / 4;
#pragma unroll
        for (int i = tid; i < V4A; i += 256) {
            int flat = i * 4;
            int r = flat / BK, c = flat % BK;
            int gr = row0 + r;
            float4 val = make_float4(0.f, 0.f, 0.f, 0.f);
            if (gr < M) val = *reinterpret_cast<const float4*>(&A[(size_t)gr * K + k0 + c]);
            As_t[c + 0][r] = val.x;
            As_t[c + 1][r] = val.y;
            As_t[c + 2][r] = val.z;
            As_t[c + 3][r] = val.w;
        }
        constexpr int V4B = BK * BN / 4;
#pragma unroll
        for (int i = tid; i < V4B; i += 256) {
            int flat = i * 4;
            int r = flat / BN, c = flat % BN;
            float4 val = *reinterpret_cast<const float4*>(&B[(size_t)(k0 + r) * N + c]);
            *reinterpret_cast<float4*>(&Bs[r][c]) = val;
        }
        __syncthreads();

#pragma unroll
        for (int kk = 0; kk < BK; ++kk) {
            float a[TM], b[TN];
#pragma unroll
            for (int j = 0; j < TM; ++j) a[j] = As_t[kk][ty * TM + j];
#pragma unroll
            for (int i = 0; i < TN; ++i) b[i] = Bs[kk][tx * TN + i];
#pragma unroll
            for (int j = 0; j < TM; ++j)
#pragma unroll
                for (int i = 0; i < TN; ++i) acc[j][i] += a[j] * b[i];
        }
        __syncthreads();
    }

#pragma unroll
    for (int j = 0; j < TM; ++j) {
        int gr = row0 + ty * TM + j;
        if (gr < M) {
            float s = dinv[gr];
            if constexpr (TN == 4) {
                float4 o;
                o.x = acc[j][0] * s; o.y = acc[j][1] * s;
                o.z = acc[j][2] * s; o.w = acc[j][3] * s;
                *reinterpret_cast<float4*>(&C[(size_t)gr * N + tx * TN]) = o;
            } else if constexpr (TN == 2) {
                float2 o;
                o.x = acc[j][0] * s; o.y = acc[j][1] * s;
                *reinterpret_cast<float2*>(&C[(size_t)gr * N + tx * TN]) = o;
            } else {
#pragma unroll
                for (int i = 0; i < TN; ++i) C[(size_t)gr * N + tx * TN + i] = acc[j][i] * s;
            }
        }
    }
}

// ---------------- Aggregation layer 1: wave per node, lane = feature (64) ----------------

__global__ __launch_bounds__(256) void agg1_kernel(const float* __restrict__ g1,
                                                   const int* __restrict__ row_off,
                                                   const int* __restrict__ deg,
                                                   const int* __restrict__ csr,
                                                   const float* __restrict__ dinv,
                                                   const float* __restrict__ b1,
                                                   float* __restrict__ h1, int n) {
    int node = (blockIdx.x * 256 + threadIdx.x) >> 6;
    int lane = threadIdx.x & 63;
    if (node >= n) return;
    float bias = b1[lane];
    float dn = dinv[node];
    int start = row_off[node];
    int cnt = deg[node];
    int end = start + cnt;
    float acc = g1[(size_t)node * F1 + lane];  // self loop
    int e = start;
    for (; e + 8 <= end; e += 8) {
        int s0 = csr[e],     s1 = csr[e + 1], s2 = csr[e + 2], s3 = csr[e + 3];
        int s4 = csr[e + 4], s5 = csr[e + 5], s6 = csr[e + 6], s7 = csr[e + 7];
        float v0 = g1[(size_t)s0 * F1 + lane];
        float v1 = g1[(size_t)s1 * F1 + lane];
        float v2 = g1[(size_t)s2 * F1 + lane];
        float v3 = g1[(size_t)s3 * F1 + lane];
        float v4 = g1[(size_t)s4 * F1 + lane];
        float v5 = g1[(size_t)s5 * F1 + lane];
        float v6 = g1[(size_t)s6 * F1 + lane];
        float v7 = g1[(size_t)s7 * F1 + lane];
        acc += v0; acc += v1; acc += v2; acc += v3;
        acc += v4; acc += v5; acc += v6; acc += v7;
    }
    for (; e < end; ++e) acc += g1[(size_t)csr[e] * F1 + lane];
    float out = acc * dn + bias;
    h1[(size_t)node * F1 + lane] = fmaxf(out, 0.f);
}

// ---------------- Aggregation layer 2 + per-block partial pooling ----------------

__global__ __launch_bounds__(256) void agg2_pool_kernel(const float* __restrict__ g2,
                                                        const int* __restrict__ row_off,
                                                        const int* __restrict__ deg,
                                                        const int* __restrict__ csr,
                                                        const float* __restrict__ dinv,
                                                        const float* __restrict__ b2,
                                                        float* __restrict__ partials,
                                                        int nblocks, int n) {
    int node = (blockIdx.x * 256 + threadIdx.x) >> 5;
    int lane = threadIdx.x & 31;
    float out = 0.f;
    if (node < n) {
        int start = row_off[node];
        int cnt = deg[node];
        int end = start + cnt;
        float acc = g2[(size_t)node * F2 + lane];  // self loop
        int e = start;
        for (; e + 8 <= end; e += 8) {
            int s0 = csr[e],     s1 = csr[e + 1], s2 = csr[e + 2], s3 = csr[e + 3];
            int s4 = csr[e + 4], s5 = csr[e + 5], s6 = csr[e + 6], s7 = csr[e + 7];
            float v0 = g2[(size_t)s0 * F2 + lane];
            float v1 = g2[(size_t)s1 * F2 + lane];
            float v2 = g2[(size_t)s2 * F2 + lane];
            float v3 = g2[(size_t)s3 * F2 + lane];
            float v4 = g2[(size_t)s4 * F2 + lane];
            float v5 = g2[(size_t)s5 * F2 + lane];
            float v6 = g2[(size_t)s6 * F2 + lane];
            float v7 = g2[(size_t)s7 * F2 + lane];
            acc += v0; acc += v1; acc += v2; acc += v3;
            acc += v4; acc += v5; acc += v6; acc += v7;
        }
        for (; e < end; ++e) acc += g2[(size_t)csr[e] * F2 + lane];
        out = fmaxf(acc * dinv[node] + b2[lane], 0.f);
    }
    __shared__ float sdata[256];
    sdata[threadIdx.x] = out;
    __syncthreads();
    if (threadIdx.x < 32) {
        float s = 0.f;
#pragma unroll
        for (int i = 0; i < 8; ++i) s += sdata[threadIdx.x + i * 32];
        partials[threadIdx.x * nblocks + blockIdx.x] = s;
    }
}

__global__ __launch_bounds__(256) void reduce_pool_kernel(const float* __restrict__ partials,
                                                          int nblocks,
                                                          float* __restrict__ pooled) {
    int f = blockIdx.x;
    const float* col = partials + (size_t)f * nblocks;
    float s = 0.f;
    for (int i = threadIdx.x; i < nblocks; i += 256) s += col[i];
    __shared__ float red[256];
    red[threadIdx.x] = s;
    __syncthreads();
    for (int ofs = 128; ofs > 0; ofs >>= 1) {
        if (threadIdx.x < ofs) red[threadIdx.x] += red[threadIdx.x + ofs];
        __syncthreads();
    }
    if (threadIdx.x == 0) pooled[f] = red[0];
}

__global__ __launch_bounds__(64) void final_kernel(const float* __restrict__ pooled,
                                                   const float* __restrict__ fcw,
                                                   const float* __restrict__ fcb,
                                                   float* __restrict__ out, int n) {
    if (threadIdx.x == 0) {
        double s = 0.0;
        for (int j = 0; j < F2; ++j) s += ((double)pooled[j] / (double)n) * (double)fcw[j];
        out[0] = (float)(s + (double)fcb[0]);
    }
}

// ---------------- launch ----------------

extern "C" void kernel_launch(void* const* d_in, const int* in_sizes, int n_in,
                              void* d_out, int out_size, void* d_ws, size_t ws_size,
                              hipStream_t stream) {
    const float* x   = (const float*)d_in[0];
    const int*   ei  = (const int*)d_in[1];
    const float* W1  = (const float*)d_in[2];
    const float* b1  = (const float*)d_in[3];
    const float* W2  = (const float*)d_in[4];
    const float* b2  = (const float*)d_in[5];
    const float* fcw = (const float*)d_in[6];
    const float* fcb = (const float*)d_in[7];
    float* out = (float*)d_out;

    const int N = in_sizes[0] / 256;  // 100000
    const int E = in_sizes[1] / 2;    // 3200000
    const int K1 = in_sizes[2] / F1;  // 256
    const int* src = ei;
    const int* dst = ei + E;

    const int NB = (N + BNODES - 1) >> BSH;  // 782 buckets
    const int SC = NB * NBLK;                // 400384 hist entries
    const int CH = (E + NBLK - 1) / NBLK;    // edges per hist/scatter block
    const int nb2 = (N + 7) / 8;             // agg2 blocks

    char* ws = (char*)d_ws;
    size_t off = 0;
    auto alloc = [&](size_t bytes) -> void* {
        void* p = ws + off;
        off = (off + bytes + 255) & ~(size_t)255;
        return p;
    };
    int SCcap = SC > N ? SC : N;
    int*   tmp      = (int*)alloc((size_t)SCcap * 4);
    int*   bsums    = (int*)alloc(2048);
    int*   bscan    = (int*)alloc(2048);
    int*   row_off  = (int*)alloc((size_t)N * 4);
    int*   deg      = (int*)alloc((size_t)N * 4);
    float* dinv     = (float*)alloc((size_t)N * 4);
    int*   csr      = (int*)alloc((size_t)E * 4);
    // region P: buck (E int2) aliases g1 (N*F1 floats) — buck dead before gemm1 writes g1
    size_t szP = (size_t)E * 8;
    size_t szG1 = (size_t)N * F1 * 4;
    void* P = alloc(szP > szG1 ? szP : szG1);
    int2*  buck = (int2*)P;
    float* g1   = (float*)P;
    // region Q: hist_T+hscan alias h1 — hist dead before agg1 writes h1
    size_t szH = 2 * ((((size_t)SC * 4) + 255) & ~(size_t)255);
    size_t szH1 = (size_t)N * F1 * 4;
    void* Q = alloc(szH > szH1 ? szH : szH1);
    int* hist_T = (int*)Q;
    int* hscan  = (int*)((char*)Q + ((((size_t)SC * 4) + 255) & ~(size_t)255));
    float* h1   = (float*)Q;
    float* g2       = (float*)alloc((size_t)N * F2 * 4);
    float* partials = (float*)alloc((size_t)F2 * nb2 * 4);
    float* pooled   = (float*)alloc(F2 * 4);

    // ---- CSR build via counting sort (no global atomics, dense writes) ----
    bucket_hist_kernel<<<NBLK, 256, 0, stream>>>(dst, hist_T, E, CH, NB);
    int nbS = (SC + 1023) / 1024;  // 391
    scan_blocks_kernel<<<nbS, 256, 0, stream>>>(hist_T, tmp, bsums, SC);
    scan_sums_kernel<<<1, 512, 0, stream>>>(bsums, bscan, nbS);
    scan_add_kernel<<<(SC + 255) / 256, 256, 0, stream>>>(tmp, bscan, hscan, SC);
    bucket_scatter_kernel<<<NBLK, 256, 0, stream>>>(src, dst, hscan, buck, E, CH, NB);
    bucket_deg_kernel<<<NB, 256, 0, stream>>>(buck, hscan, deg, dinv, E, N, NB);
    int nbS2 = (N + 1023) / 1024;  // 98
    scan_blocks_kernel<<<nbS2, 256, 0, stream>>>(deg, tmp, bsums, N);
    scan_sums_kernel<<<1, 512, 0, stream>>>(bsums, bscan, nbS2);
    scan_add_kernel<<<(N + 255) / 256, 256, 0, stream>>>(tmp, bscan, row_off, N);
    bucket_fill_kernel<<<NB, 256, 0, stream>>>(buck, hscan, row_off, csr, E, N, NB);

    // ---- layer 1: g1 = (x @ W1) * dinv ----
    gemm_scale_kernel<128, 64, 32, 8, 4><<<(N + 127) / 128, 256, 0, stream>>>(x, W1, dinv, g1, N, K1, F1);
    agg1_kernel<<<(N + 3) / 4, 256, 0, stream>>>(g1, row_off, deg, csr, dinv, b1, h1, N);

    // ---- layer 2: g2 = (h1 @ W2) * dinv ----
    gemm_scale_kernel<128, 32, 32, 8, 2><<<(N + 127) / 128, 256, 0, stream>>>(h1, W2, dinv, g2, N, F1, F2);
    agg2_pool_kernel<<<nb2, 256, 0, stream>>>(g2, row_off, deg, csr, dinv, b2, partials, nb2, N);

    reduce_pool_kernel<<<F2, 256, 0, stream>>>(partials, nb2, pooled);
    final_kernel<<<1, 64, 0, stream>>>(pooled, fcw, fcb, out, N);
}

// Round 4
// 318.857 us; speedup vs baseline: 2.6105x; 1.1200x over previous
//
#include <hip/hip_runtime.h>
#include <hip/hip_fp16.h>

#ifndef F1
#define F1 64
#define F2 32
#endif

#define NBLK 512     // blocks for bucket hist/scatter passes
#define BSH  7       // bucket = dst >> 7  (128 nodes per bucket)
#define BNODES 128

// ---------------- scans (generic) ----------------
__global__ __launch_bounds__(256) void scan_blocks_kernel(const int* __restrict__ in,
                                                          int* __restrict__ tmp,
                                                          int* __restrict__ blk_sums, int n) {
    __shared__ int sdata[256];
    int t = threadIdx.x;
    int base = blockIdx.x * 1024 + t * 4;
    int v[4];
#pragma unroll
    for (int j = 0; j < 4; ++j) v[j] = (base + j < n) ? in[base + j] : 0;
    int mysum = v[0] + v[1] + v[2] + v[3];
    sdata[t] = mysum;
    __syncthreads();
    for (int ofs = 1; ofs < 256; ofs <<= 1) {
        int val = (t >= ofs) ? sdata[t - ofs] : 0;
        __syncthreads();
        sdata[t] += val;
        __syncthreads();
    }
    int incl = sdata[t];
    int excl = incl - mysum;
    if (t == 255) blk_sums[blockIdx.x] = incl;
    int run = excl;
#pragma unroll
    for (int j = 0; j < 4; ++j) {
        if (base + j < n) tmp[base + j] = run;
        run += v[j];
    }
}

__global__ __launch_bounds__(512) void scan_sums_kernel(const int* __restrict__ blk_sums,
                                                        int* __restrict__ blk_scanned, int nb) {
    __shared__ int sdata[512];
    int t = threadIdx.x;
    int mine = (t < nb) ? blk_sums[t] : 0;
    sdata[t] = mine;
    __syncthreads();
    for (int ofs = 1; ofs < 512; ofs <<= 1) {
        int val = (t >= ofs) ? sdata[t - ofs] : 0;
        __syncthreads();
        sdata[t] += val;
        __syncthreads();
    }
    blk_scanned[t] = sdata[t] - mine;  // exclusive
}

__global__ __launch_bounds__(256) void scan_add_kernel(const int* __restrict__ tmp,
                                                       const int* __restrict__ blk_scanned,
                                                       int* __restrict__ out, int n) {
    int i = blockIdx.x * 256 + threadIdx.x;
    if (i < n) out[i] = tmp[i] + blk_scanned[i >> 10];
}

// ---------------- bucket passes (counting sort by dst>>BSH) ----------------

__global__ __launch_bounds__(256) void bucket_hist_kernel(const int* __restrict__ dst,
                                                          int* __restrict__ hist_T,
                                                          int E, int CH, int NB) {
    __shared__ int lh[1024];
    int b = blockIdx.x;
    for (int i = threadIdx.x; i < NB; i += 256) lh[i] = 0;
    __syncthreads();
    int start = b * CH, end = min(E, start + CH);
    for (int e = start + threadIdx.x; e < end; e += 256)
        atomicAdd(&lh[dst[e] >> BSH], 1);
    __syncthreads();
    for (int k = threadIdx.x; k < NB; k += 256)
        hist_T[k * NBLK + b] = lh[k];
}

// Scatter packed (src<<7)|(dst&127) into contiguous bucket regions.
__global__ __launch_bounds__(256) void bucket_scatter_kernel(const int* __restrict__ src,
                                                             const int* __restrict__ dst,
                                                             const int* __restrict__ hscan,
                                                             int* __restrict__ buck,
                                                             int E, int CH, int NB) {
    __shared__ int cur[1024];
    int b = blockIdx.x;
    for (int i = threadIdx.x; i < NB; i += 256) cur[i] = hscan[i * NBLK + b];
    __syncthreads();
    int start = b * CH, end = min(E, start + CH);
    for (int e = start + threadIdx.x; e < end; e += 256) {
        int d = dst[e];
        int pos = atomicAdd(&cur[d >> BSH], 1);
        buck[pos] = (src[e] << BSH) | (d & (BNODES - 1));
    }
}

__global__ __launch_bounds__(256) void bucket_deg_kernel(const int* __restrict__ buck,
                                                         const int* __restrict__ hscan,
                                                         int* __restrict__ deg,
                                                         float* __restrict__ dinv,
                                                         int E, int N, int NB) {
    __shared__ int cnt[BNODES];
    int k = blockIdx.x;
    if (threadIdx.x < BNODES) cnt[threadIdx.x] = 0;
    __syncthreads();
    int bs = hscan[k * NBLK];
    int be = (k + 1 < NB) ? hscan[(k + 1) * NBLK] : E;
    for (int e = bs + threadIdx.x; e < be; e += 256)
        atomicAdd(&cnt[buck[e] & (BNODES - 1)], 1);
    __syncthreads();
    int node0 = k << BSH;
    int i = node0 + threadIdx.x;
    if (threadIdx.x < BNODES && i < N) {
        int c = cnt[threadIdx.x];
        deg[i] = c;
        dinv[i] = rsqrtf((float)(c + 1));  // +1 self loop
    }
}

__global__ __launch_bounds__(256) void bucket_fill_kernel(const int* __restrict__ buck,
                                                          const int* __restrict__ hscan,
                                                          const int* __restrict__ row_off,
                                                          int* __restrict__ csr,
                                                          int E, int N, int NB) {
    __shared__ int lrow[BNODES];
    __shared__ int lcur[BNODES];
    int k = blockIdx.x;
    int node0 = k << BSH;
    if (threadIdx.x < BNODES) {
        lcur[threadIdx.x] = 0;
        int i = node0 + threadIdx.x;
        lrow[threadIdx.x] = (i < N) ? row_off[i] : 0;
    }
    __syncthreads();
    int bs = hscan[k * NBLK];
    int be = (k + 1 < NB) ? hscan[(k + 1) * NBLK] : E;
    for (int e = bs + threadIdx.x; e < be; e += 256) {
        int p = buck[e];
        int li = p & (BNODES - 1);
        int pos = lrow[li] + atomicAdd(&lcur[li], 1);
        csr[pos] = p >> BSH;
    }
}

// ---------------- GEMM (f32 vector ALU), C = half((A @ B) * dinv[row]) ----------------

template <int BM, int BN, int BK, int TM, int TN>
__global__ __launch_bounds__(256) void gemm_scale_kernel(const float* __restrict__ A,
                                                         const float* __restrict__ B,
                                                         const float* __restrict__ dinv,
                                                         __half* __restrict__ C,
                                                         int M, int K, int N) {
    constexpr int TX = BN / TN;
    __shared__ float As_t[BK][BM + 4];  // transposed A tile, padded
    __shared__ float Bs[BK][BN + 4];

    int tid = threadIdx.x;
    int tx = tid % TX, ty = tid / TX;
    int row0 = blockIdx.x * BM;

    float acc[TM][TN];
#pragma unroll
    for (int j = 0; j < TM; ++j)
#pragma unroll
        for (int i = 0; i < TN; ++i) acc[j][i] = 0.f;

    for (int k0 = 0; k0 < K; k0 += BK) {
        constexpr int V4A = BM * BK / 4;
#pragma unroll
        for (int i = tid; i < V4A; i += 256) {
            int flat = i * 4;
            int r = flat / BK, c = flat % BK;
            int gr = row0 + r;
            float4 val = make_float4(0.f, 0.f, 0.f, 0.f);
            if (gr < M) val = *reinterpret_cast<const float4*>(&A[(size_t)gr * K + k0 + c]);
            As_t[c + 0][r] = val.x;
            As_t[c + 1][r] = val.y;
            As_t[c + 2][r] = val.z;
            As_t[c + 3][r] = val.w;
        }
        constexpr int V4B = BK * BN / 4;
#pragma unroll
        for (int i = tid; i < V4B; i += 256) {
            int flat = i * 4;
            int r = flat / BN, c = flat % BN;
            float4 val = *reinterpret_cast<const float4*>(&B[(size_t)(k0 + r) * N + c]);
            *reinterpret_cast<float4*>(&Bs[r][c]) = val;
        }
        __syncthreads();

#pragma unroll
        for (int kk = 0; kk < BK; ++kk) {
            float a[TM], b[TN];
#pragma unroll
            for (int j = 0; j < TM; ++j) a[j] = As_t[kk][ty * TM + j];
#pragma unroll
            for (int i = 0; i < TN; ++i) b[i] = Bs[kk][tx * TN + i];
#pragma unroll
            for (int j = 0; j < TM; ++j)
#pragma unroll
                for (int i = 0; i < TN; ++i) acc[j][i] += a[j] * b[i];
        }
        __syncthreads();
    }

#pragma unroll
    for (int j = 0; j < TM; ++j) {
        int gr = row0 + ty * TM + j;
        if (gr < M) {
            float s = dinv[gr];
            __half h[TN];
#pragma unroll
            for (int i = 0; i < TN; ++i) h[i] = __float2half(acc[j][i] * s);
            if constexpr (TN == 4) {
                *reinterpret_cast<uint2*>(&C[(size_t)gr * N + tx * TN]) =
                    *reinterpret_cast<const uint2*>(h);
            } else if constexpr (TN == 2) {
                *reinterpret_cast<unsigned*>(&C[(size_t)gr * N + tx * TN]) =
                    *reinterpret_cast<const unsigned*>(h);
            } else {
#pragma unroll
                for (int i = 0; i < TN; ++i) C[(size_t)gr * N + tx * TN + i] = h[i];
            }
        }
    }
}

// ---------------- Aggregation layer 1: wave per node, lane = feature (64) ----------------

__global__ __launch_bounds__(256) void agg1_kernel(const __half* __restrict__ g1,
                                                   const int* __restrict__ row_off,
                                                   const int* __restrict__ deg,
                                                   const int* __restrict__ csr,
                                                   const float* __restrict__ dinv,
                                                   const float* __restrict__ b1,
                                                   float* __restrict__ h1, int n) {
    int node = (blockIdx.x * 256 + threadIdx.x) >> 6;
    int lane = threadIdx.x & 63;
    if (node >= n) return;
    float bias = b1[lane];
    float dn = dinv[node];
    int start = row_off[node];
    int cnt = deg[node];
    int end = start + cnt;
    float acc = __half2float(g1[(size_t)node * F1 + lane]);  // self loop
    int e = start;
    for (; e + 8 <= end; e += 8) {
        int s0 = csr[e],     s1 = csr[e + 1], s2 = csr[e + 2], s3 = csr[e + 3];
        int s4 = csr[e + 4], s5 = csr[e + 5], s6 = csr[e + 6], s7 = csr[e + 7];
        float v0 = __half2float(g1[(size_t)s0 * F1 + lane]);
        float v1 = __half2float(g1[(size_t)s1 * F1 + lane]);
        float v2 = __half2float(g1[(size_t)s2 * F1 + lane]);
        float v3 = __half2float(g1[(size_t)s3 * F1 + lane]);
        float v4 = __half2float(g1[(size_t)s4 * F1 + lane]);
        float v5 = __half2float(g1[(size_t)s5 * F1 + lane]);
        float v6 = __half2float(g1[(size_t)s6 * F1 + lane]);
        float v7 = __half2float(g1[(size_t)s7 * F1 + lane]);
        acc += v0; acc += v1; acc += v2; acc += v3;
        acc += v4; acc += v5; acc += v6; acc += v7;
    }
    for (; e < end; ++e) acc += __half2float(g1[(size_t)csr[e] * F1 + lane]);
    float out = acc * dn + bias;
    h1[(size_t)node * F1 + lane] = fmaxf(out, 0.f);
}

// ---------------- Aggregation layer 2 + per-block partial pooling ----------------

__global__ __launch_bounds__(256) void agg2_pool_kernel(const __half* __restrict__ g2,
                                                        const int* __restrict__ row_off,
                                                        const int* __restrict__ deg,
                                                        const int* __restrict__ csr,
                                                        const float* __restrict__ dinv,
                                                        const float* __restrict__ b2,
                                                        float* __restrict__ partials,
                                                        int nblocks, int n) {
    int node = (blockIdx.x * 256 + threadIdx.x) >> 5;
    int lane = threadIdx.x & 31;
    float out = 0.f;
    if (node < n) {
        int start = row_off[node];
        int cnt = deg[node];
        int end = start + cnt;
        float acc = __half2float(g2[(size_t)node * F2 + lane]);  // self loop
        int e = start;
        for (; e + 8 <= end; e += 8) {
            int s0 = csr[e],     s1 = csr[e + 1], s2 = csr[e + 2], s3 = csr[e + 3];
            int s4 = csr[e + 4], s5 = csr[e + 5], s6 = csr[e + 6], s7 = csr[e + 7];
            float v0 = __half2float(g2[(size_t)s0 * F2 + lane]);
            float v1 = __half2float(g2[(size_t)s1 * F2 + lane]);
            float v2 = __half2float(g2[(size_t)s2 * F2 + lane]);
            float v3 = __half2float(g2[(size_t)s3 * F2 + lane]);
            float v4 = __half2float(g2[(size_t)s4 * F2 + lane]);
            float v5 = __half2float(g2[(size_t)s5 * F2 + lane]);
            float v6 = __half2float(g2[(size_t)s6 * F2 + lane]);
            float v7 = __half2float(g2[(size_t)s7 * F2 + lane]);
            acc += v0; acc += v1; acc += v2; acc += v3;
            acc += v4; acc += v5; acc += v6; acc += v7;
        }
        for (; e < end; ++e) acc += __half2float(g2[(size_t)csr[e] * F2 + lane]);
        out = fmaxf(acc * dinv[node] + b2[lane], 0.f);
    }
    __shared__ float sdata[256];
    sdata[threadIdx.x] = out;
    __syncthreads();
    if (threadIdx.x < 32) {
        float s = 0.f;
#pragma unroll
        for (int i = 0; i < 8; ++i) s += sdata[threadIdx.x + i * 32];
        partials[threadIdx.x * nblocks + blockIdx.x] = s;
    }
}

__global__ __launch_bounds__(256) void reduce_pool_kernel(const float* __restrict__ partials,
                                                          int nblocks,
                                                          float* __restrict__ pooled) {
    int f = blockIdx.x;
    const float* col = partials + (size_t)f * nblocks;
    float s = 0.f;
    for (int i = threadIdx.x; i < nblocks; i += 256) s += col[i];
    __shared__ float red[256];
    red[threadIdx.x] = s;
    __syncthreads();
    for (int ofs = 128; ofs > 0; ofs >>= 1) {
        if (threadIdx.x < ofs) red[threadIdx.x] += red[threadIdx.x + ofs];
        __syncthreads();
    }
    if (threadIdx.x == 0) pooled[f] = red[0];
}

__global__ __launch_bounds__(64) void final_kernel(const float* __restrict__ pooled,
                                                   const float* __restrict__ fcw,
                                                   const float* __restrict__ fcb,
                                                   float* __restrict__ out, int n) {
    if (threadIdx.x == 0) {
        double s = 0.0;
        for (int j = 0; j < F2; ++j) s += ((double)pooled[j] / (double)n) * (double)fcw[j];
        out[0] = (float)(s + (double)fcb[0]);
    }
}

// ---------------- launch ----------------

extern "C" void kernel_launch(void* const* d_in, const int* in_sizes, int n_in,
                              void* d_out, int out_size, void* d_ws, size_t ws_size,
                              hipStream_t stream) {
    const float* x   = (const float*)d_in[0];
    const int*   ei  = (const int*)d_in[1];
    const float* W1  = (const float*)d_in[2];
    const float* b1  = (const float*)d_in[3];
    const float* W2  = (const float*)d_in[4];
    const float* b2  = (const float*)d_in[5];
    const float* fcw = (const float*)d_in[6];
    const float* fcb = (const float*)d_in[7];
    float* out = (float*)d_out;

    const int N = in_sizes[0] / 256;  // 100000
    const int E = in_sizes[1] / 2;    // 3200000
    const int K1 = in_sizes[2] / F1;  // 256
    const int* src = ei;
    const int* dst = ei + E;

    const int NB = (N + BNODES - 1) >> BSH;  // 782 buckets
    const int SC = NB * NBLK;                // 400384 hist entries
    const int CH = (E + NBLK - 1) / NBLK;    // edges per hist/scatter block
    const int nb2 = (N + 7) / 8;             // agg2 blocks

    char* ws = (char*)d_ws;
    size_t off = 0;
    auto alloc = [&](size_t bytes) -> void* {
        void* p = ws + off;
        off = (off + bytes + 255) & ~(size_t)255;
        return p;
    };
    int SCcap = SC > N ? SC : N;
    int*   tmp      = (int*)alloc((size_t)SCcap * 4);
    int*   bsums    = (int*)alloc(2048);
    int*   bscan    = (int*)alloc(2048);
    int*   row_off  = (int*)alloc((size_t)N * 4);
    int*   deg      = (int*)alloc((size_t)N * 4);
    float* dinv     = (float*)alloc((size_t)N * 4);
    int*   csr      = (int*)alloc((size_t)E * 4);
    // region P: buck (E int) aliases g1 (N*F1 halves) — buck dead before gemm1 writes g1
    size_t szP = (size_t)E * 4;
    size_t szG1 = (size_t)N * F1 * 2;
    void* P = alloc(szP > szG1 ? szP : szG1);
    int*    buck = (int*)P;
    __half* g1   = (__half*)P;
    // region Q: hist_T+hscan alias h1 — hist dead before agg1 writes h1
    size_t szH = 2 * ((((size_t)SC * 4) + 255) & ~(size_t)255);
    size_t szH1 = (size_t)N * F1 * 4;
    void* Q = alloc(szH > szH1 ? szH : szH1);
    int* hist_T = (int*)Q;
    int* hscan  = (int*)((char*)Q + ((((size_t)SC * 4) + 255) & ~(size_t)255));
    float* h1   = (float*)Q;
    __half* g2      = (__half*)alloc((size_t)N * F2 * 2);
    float* partials = (float*)alloc((size_t)F2 * nb2 * 4);
    float* pooled   = (float*)alloc(F2 * 4);

    // ---- CSR build via counting sort (no global atomics, dense writes) ----
    bucket_hist_kernel<<<NBLK, 256, 0, stream>>>(dst, hist_T, E, CH, NB);
    int nbS = (SC + 1023) / 1024;  // 391
    scan_blocks_kernel<<<nbS, 256, 0, stream>>>(hist_T, tmp, bsums, SC);
    scan_sums_kernel<<<1, 512, 0, stream>>>(bsums, bscan, nbS);
    scan_add_kernel<<<(SC + 255) / 256, 256, 0, stream>>>(tmp, bscan, hscan, SC);
    bucket_scatter_kernel<<<NBLK, 256, 0, stream>>>(src, dst, hscan, buck, E, CH, NB);
    bucket_deg_kernel<<<NB, 256, 0, stream>>>(buck, hscan, deg, dinv, E, N, NB);
    int nbS2 = (N + 1023) / 1024;  // 98
    scan_blocks_kernel<<<nbS2, 256, 0, stream>>>(deg, tmp, bsums, N);
    scan_sums_kernel<<<1, 512, 0, stream>>>(bsums, bscan, nbS2);
    scan_add_kernel<<<(N + 255) / 256, 256, 0, stream>>>(tmp, bscan, row_off, N);
    bucket_fill_kernel<<<NB, 256, 0, stream>>>(buck, hscan, row_off, csr, E, N, NB);

    // ---- layer 1: g1 = half((x @ W1) * dinv) ----
    gemm_scale_kernel<128, 64, 32, 8, 4><<<(N + 127) / 128, 256, 0, stream>>>(x, W1, dinv, g1, N, K1, F1);
    agg1_kernel<<<(N + 3) / 4, 256, 0, stream>>>(g1, row_off, deg, csr, dinv, b1, h1, N);

    // ---- layer 2: g2 = half((h1 @ W2) * dinv) ----
    gemm_scale_kernel<128, 32, 32, 8, 2><<<(N + 127) / 128, 256, 0, stream>>>(h1, W2, dinv, g2, N, F1, F2);
    agg2_pool_kernel<<<nb2, 256, 0, stream>>>(g2, row_off, deg, csr, dinv, b2, partials, nb2, N);

    reduce_pool_kernel<<<F2, 256, 0, stream>>>(partials, nb2, pooled);
    final_kernel<<<1, 64, 0, stream>>>(pooled, fcw, fcb, out, N);
}

// Round 5
// 304.443 us; speedup vs baseline: 2.7341x; 1.0473x over previous
//
#include <hip/hip_runtime.h>
#include <hip/hip_fp16.h>

#ifndef F1
#define F1 64
#define F2 32
#endif

#define NBLK 512     // blocks for bucket hist/scatter passes
#define BSH  7       // bucket = dst >> 7  (128 nodes per bucket)
#define BNODES 128

// ---------------- scans (generic) ----------------
__global__ __launch_bounds__(256) void scan_blocks_kernel(const int* __restrict__ in,
                                                          int* __restrict__ tmp,
                                                          int* __restrict__ blk_sums, int n) {
    __shared__ int sdata[256];
    int t = threadIdx.x;
    int base = blockIdx.x * 1024 + t * 4;
    int v[4];
#pragma unroll
    for (int j = 0; j < 4; ++j) v[j] = (base + j < n) ? in[base + j] : 0;
    int mysum = v[0] + v[1] + v[2] + v[3];
    sdata[t] = mysum;
    __syncthreads();
    for (int ofs = 1; ofs < 256; ofs <<= 1) {
        int val = (t >= ofs) ? sdata[t - ofs] : 0;
        __syncthreads();
        sdata[t] += val;
        __syncthreads();
    }
    int incl = sdata[t];
    int excl = incl - mysum;
    if (t == 255) blk_sums[blockIdx.x] = incl;
    int run = excl;
#pragma unroll
    for (int j = 0; j < 4; ++j) {
        if (base + j < n) tmp[base + j] = run;
        run += v[j];
    }
}

__global__ __launch_bounds__(512) void scan_sums_kernel(const int* __restrict__ blk_sums,
                                                        int* __restrict__ blk_scanned, int nb) {
    __shared__ int sdata[512];
    int t = threadIdx.x;
    int mine = (t < nb) ? blk_sums[t] : 0;
    sdata[t] = mine;
    __syncthreads();
    for (int ofs = 1; ofs < 512; ofs <<= 1) {
        int val = (t >= ofs) ? sdata[t - ofs] : 0;
        __syncthreads();
        sdata[t] += val;
        __syncthreads();
    }
    blk_scanned[t] = sdata[t] - mine;  // exclusive
}

__global__ __launch_bounds__(256) void scan_add_kernel(const int* __restrict__ tmp,
                                                       const int* __restrict__ blk_scanned,
                                                       int* __restrict__ out, int n) {
    int i = blockIdx.x * 256 + threadIdx.x;
    if (i < n) out[i] = tmp[i] + blk_scanned[i >> 10];
}

// ---------------- bucket passes (counting sort by dst>>BSH) ----------------

__global__ __launch_bounds__(256) void bucket_hist_kernel(const int* __restrict__ dst,
                                                          int* __restrict__ hist_T,
                                                          int E, int CH, int NB) {
    __shared__ int lh[1024];
    int b = blockIdx.x;
    for (int i = threadIdx.x; i < NB; i += 256) lh[i] = 0;
    __syncthreads();
    int start = b * CH, end = min(E, start + CH);
    for (int e = start + threadIdx.x; e < end; e += 256)
        atomicAdd(&lh[dst[e] >> BSH], 1);
    __syncthreads();
    for (int k = threadIdx.x; k < NB; k += 256)
        hist_T[k * NBLK + b] = lh[k];
}

// Scatter packed (src<<7)|(dst&127) into contiguous bucket regions.
__global__ __launch_bounds__(256) void bucket_scatter_kernel(const int* __restrict__ src,
                                                             const int* __restrict__ dst,
                                                             const int* __restrict__ hscan,
                                                             int* __restrict__ buck,
                                                             int E, int CH, int NB) {
    __shared__ int cur[1024];
    int b = blockIdx.x;
    for (int i = threadIdx.x; i < NB; i += 256) cur[i] = hscan[i * NBLK + b];
    __syncthreads();
    int start = b * CH, end = min(E, start + CH);
    for (int e = start + threadIdx.x; e < end; e += 256) {
        int d = dst[e];
        int pos = atomicAdd(&cur[d >> BSH], 1);
        buck[pos] = (src[e] << BSH) | (d & (BNODES - 1));
    }
}

__global__ __launch_bounds__(256) void bucket_deg_kernel(const int* __restrict__ buck,
                                                         const int* __restrict__ hscan,
                                                         int* __restrict__ deg,
                                                         float* __restrict__ dinv,
                                                         int E, int N, int NB) {
    __shared__ int cnt[BNODES];
    int k = blockIdx.x;
    if (threadIdx.x < BNODES) cnt[threadIdx.x] = 0;
    __syncthreads();
    int bs = hscan[k * NBLK];
    int be = (k + 1 < NB) ? hscan[(k + 1) * NBLK] : E;
    for (int e = bs + threadIdx.x; e < be; e += 256)
        atomicAdd(&cnt[buck[e] & (BNODES - 1)], 1);
    __syncthreads();
    int node0 = k << BSH;
    int i = node0 + threadIdx.x;
    if (threadIdx.x < BNODES && i < N) {
        int c = cnt[threadIdx.x];
        deg[i] = c;
        dinv[i] = rsqrtf((float)(c + 1));  // +1 self loop
    }
}

__global__ __launch_bounds__(256) void bucket_fill_kernel(const int* __restrict__ buck,
                                                          const int* __restrict__ hscan,
                                                          const int* __restrict__ row_off,
                                                          int* __restrict__ csr,
                                                          int E, int N, int NB) {
    __shared__ int lrow[BNODES];
    __shared__ int lcur[BNODES];
    int k = blockIdx.x;
    int node0 = k << BSH;
    if (threadIdx.x < BNODES) {
        lcur[threadIdx.x] = 0;
        int i = node0 + threadIdx.x;
        lrow[threadIdx.x] = (i < N) ? row_off[i] : 0;
    }
    __syncthreads();
    int bs = hscan[k * NBLK];
    int be = (k + 1 < NB) ? hscan[(k + 1) * NBLK] : E;
    for (int e = bs + threadIdx.x; e < be; e += 256) {
        int p = buck[e];
        int li = p & (BNODES - 1);
        int pos = lrow[li] + atomicAdd(&lcur[li], 1);
        csr[pos] = p >> BSH;
    }
}

// ---------------- GEMM (f32 vector ALU), C = half((A @ B) * dinv[row]) ----------------

template <int BM, int BN, int BK, int TM, int TN>
__global__ __launch_bounds__(256) void gemm_scale_kernel(const float* __restrict__ A,
                                                         const float* __restrict__ B,
                                                         const float* __restrict__ dinv,
                                                         __half* __restrict__ C,
                                                         int M, int K, int N) {
    constexpr int TX = BN / TN;
    __shared__ float As_t[BK][BM + 4];  // transposed A tile, padded
    __shared__ float Bs[BK][BN + 4];

    int tid = threadIdx.x;
    int tx = tid % TX, ty = tid / TX;
    int row0 = blockIdx.x * BM;

    float acc[TM][TN];
#pragma unroll
    for (int j = 0; j < TM; ++j)
#pragma unroll
        for (int i = 0; i < TN; ++i) acc[j][i] = 0.f;

    for (int k0 = 0; k0 < K; k0 += BK) {
        constexpr int V4A = BM * BK / 4;
#pragma unroll
        for (int i = tid; i < V4A; i += 256) {
            int flat = i * 4;
            int r = flat / BK, c = flat % BK;
            int gr = row0 + r;
            float4 val = make_float4(0.f, 0.f, 0.f, 0.f);
            if (gr < M) val = *reinterpret_cast<const float4*>(&A[(size_t)gr * K + k0 + c]);
            As_t[c + 0][r] = val.x;
            As_t[c + 1][r] = val.y;
            As_t[c + 2][r] = val.z;
            As_t[c + 3][r] = val.w;
        }
        constexpr int V4B = BK * BN / 4;
#pragma unroll
        for (int i = tid; i < V4B; i += 256) {
            int flat = i * 4;
            int r = flat / BN, c = flat % BN;
            float4 val = *reinterpret_cast<const float4*>(&B[(size_t)(k0 + r) * N + c]);
            *reinterpret_cast<float4*>(&Bs[r][c]) = val;
        }
        __syncthreads();

#pragma unroll
        for (int kk = 0; kk < BK; ++kk) {
            float a[TM], b[TN];
#pragma unroll
            for (int j = 0; j < TM; ++j) a[j] = As_t[kk][ty * TM + j];
#pragma unroll
            for (int i = 0; i < TN; ++i) b[i] = Bs[kk][tx * TN + i];
#pragma unroll
            for (int j = 0; j < TM; ++j)
#pragma unroll
                for (int i = 0; i < TN; ++i) acc[j][i] += a[j] * b[i];
        }
        __syncthreads();
    }

#pragma unroll
    for (int j = 0; j < TM; ++j) {
        int gr = row0 + ty * TM + j;
        if (gr < M) {
            float s = dinv[gr];
            __half h[TN];
#pragma unroll
            for (int i = 0; i < TN; ++i) h[i] = __float2half(acc[j][i] * s);
            if constexpr (TN == 4) {
                *reinterpret_cast<uint2*>(&C[(size_t)gr * N + tx * TN]) =
                    *reinterpret_cast<const uint2*>(h);
            } else if constexpr (TN == 2) {
                *reinterpret_cast<unsigned*>(&C[(size_t)gr * N + tx * TN]) =
                    *reinterpret_cast<const unsigned*>(h);
            } else {
#pragma unroll
                for (int i = 0; i < TN; ++i) C[(size_t)gr * N + tx * TN + i] = h[i];
            }
        }
    }
}

// ---------------- gather helpers ----------------

__device__ __forceinline__ void acc_row8(const __half* __restrict__ base,
                                         float& a0, float& a1, float& a2, float& a3) {
    uint2 raw = *reinterpret_cast<const uint2*>(base);
    __half2 h01 = *reinterpret_cast<const __half2*>(&raw.x);
    __half2 h23 = *reinterpret_cast<const __half2*>(&raw.y);
    float2 f01 = __half22float2(h01);
    float2 f23 = __half22float2(h23);
    a0 += f01.x; a1 += f01.y; a2 += f23.x; a3 += f23.y;
}

// ---------------- Aggregation layer 1: wave per node ----------------
// 64 lanes = 4 edge-groups x 16 feature-quads. Each lane loads 8B (4 halves);
// one dwordx2 per group covers a full 64-feature row; wave does 4 edges/load.

__global__ __launch_bounds__(256) void agg1_kernel(const __half* __restrict__ g1,
                                                   const int* __restrict__ row_off,
                                                   const int* __restrict__ deg,
                                                   const int* __restrict__ csr,
                                                   const float* __restrict__ dinv,
                                                   const float* __restrict__ b1,
                                                   float* __restrict__ h1, int n) {
    int node = (blockIdx.x * 256 + threadIdx.x) >> 6;
    int lane = threadIdx.x & 63;
    int g = lane >> 4;        // edge group 0..3
    int f4 = lane & 15;       // feature quad 0..15
    if (node >= n) return;
    int start = row_off[node];
    int end = start + deg[node];
    float a0 = 0.f, a1 = 0.f, a2 = 0.f, a3 = 0.f;
    if (g == 0)  // self loop counted once
        acc_row8(g1 + ((size_t)node << 6) + f4 * 4, a0, a1, a2, a3);
    int e = start;
    for (; e + 16 <= end; e += 16) {
        int s0 = csr[e + g];
        int s1 = csr[e + 4 + g];
        int s2 = csr[e + 8 + g];
        int s3 = csr[e + 12 + g];
        acc_row8(g1 + ((size_t)s0 << 6) + f4 * 4, a0, a1, a2, a3);
        acc_row8(g1 + ((size_t)s1 << 6) + f4 * 4, a0, a1, a2, a3);
        acc_row8(g1 + ((size_t)s2 << 6) + f4 * 4, a0, a1, a2, a3);
        acc_row8(g1 + ((size_t)s3 << 6) + f4 * 4, a0, a1, a2, a3);
    }
    for (; e + 4 <= end; e += 4) {
        int s = csr[e + g];
        acc_row8(g1 + ((size_t)s << 6) + f4 * 4, a0, a1, a2, a3);
    }
    if (e + g < end) {
        int s = csr[e + g];
        acc_row8(g1 + ((size_t)s << 6) + f4 * 4, a0, a1, a2, a3);
    }
    // fold the 4 edge groups (feature quad f4 lives in lanes f4, 16+f4, 32+f4, 48+f4)
    a0 += __shfl_xor(a0, 16); a1 += __shfl_xor(a1, 16);
    a2 += __shfl_xor(a2, 16); a3 += __shfl_xor(a3, 16);
    a0 += __shfl_xor(a0, 32); a1 += __shfl_xor(a1, 32);
    a2 += __shfl_xor(a2, 32); a3 += __shfl_xor(a3, 32);
    if (g == 0) {
        float dn = dinv[node];
        float4 bias = *reinterpret_cast<const float4*>(b1 + f4 * 4);
        float4 o;
        o.x = fmaxf(a0 * dn + bias.x, 0.f);
        o.y = fmaxf(a1 * dn + bias.y, 0.f);
        o.z = fmaxf(a2 * dn + bias.z, 0.f);
        o.w = fmaxf(a3 * dn + bias.w, 0.f);
        *reinterpret_cast<float4*>(h1 + ((size_t)node << 6) + f4 * 4) = o;
    }
}

// ---------------- Aggregation layer 2 + pooling: wave per node ----------------
// 64 lanes = 8 edge-groups x 8 feature-quads (F2=32). 8 edges per load.

__global__ __launch_bounds__(256) void agg2_pool_kernel(const __half* __restrict__ g2,
                                                        const int* __restrict__ row_off,
                                                        const int* __restrict__ deg,
                                                        const int* __restrict__ csr,
                                                        const float* __restrict__ dinv,
                                                        const float* __restrict__ b2,
                                                        float* __restrict__ partials,
                                                        int nblocks, int n) {
    int node = (blockIdx.x * 256 + threadIdx.x) >> 6;
    int w = (threadIdx.x >> 6) & 3;  // wave in block
    int lane = threadIdx.x & 63;
    int g = lane >> 3;       // edge group 0..7
    int f4 = lane & 7;       // feature quad 0..7
    float a0 = 0.f, a1 = 0.f, a2 = 0.f, a3 = 0.f;
    if (node < n) {
        int start = row_off[node];
        int end = start + deg[node];
        if (g == 0)
            acc_row8(g2 + ((size_t)node << 5) + f4 * 4, a0, a1, a2, a3);
        int e = start;
        for (; e + 16 <= end; e += 16) {
            int s0 = csr[e + g];
            int s1 = csr[e + 8 + g];
            acc_row8(g2 + ((size_t)s0 << 5) + f4 * 4, a0, a1, a2, a3);
            acc_row8(g2 + ((size_t)s1 << 5) + f4 * 4, a0, a1, a2, a3);
        }
        for (; e + 8 <= end; e += 8) {
            int s = csr[e + g];
            acc_row8(g2 + ((size_t)s << 5) + f4 * 4, a0, a1, a2, a3);
        }
        if (e + g < end) {
            int s = csr[e + g];
            acc_row8(g2 + ((size_t)s << 5) + f4 * 4, a0, a1, a2, a3);
        }
        a0 += __shfl_xor(a0, 8);  a1 += __shfl_xor(a1, 8);
        a2 += __shfl_xor(a2, 8);  a3 += __shfl_xor(a3, 8);
        a0 += __shfl_xor(a0, 16); a1 += __shfl_xor(a1, 16);
        a2 += __shfl_xor(a2, 16); a3 += __shfl_xor(a3, 16);
        a0 += __shfl_xor(a0, 32); a1 += __shfl_xor(a1, 32);
        a2 += __shfl_xor(a2, 32); a3 += __shfl_xor(a3, 32);
    }
    __shared__ float sdata[4][32];
    if (g == 0) {
        float4 o = make_float4(0.f, 0.f, 0.f, 0.f);
        if (node < n) {
            float dn = dinv[node];
            float4 bias = *reinterpret_cast<const float4*>(b2 + f4 * 4);
            o.x = fmaxf(a0 * dn + bias.x, 0.f);
            o.y = fmaxf(a1 * dn + bias.y, 0.f);
            o.z = fmaxf(a2 * dn + bias.z, 0.f);
            o.w = fmaxf(a3 * dn + bias.w, 0.f);
        }
        *reinterpret_cast<float4*>(&sdata[w][f4 * 4]) = o;
    }
    __syncthreads();
    if (threadIdx.x < 32) {
        float s = sdata[0][threadIdx.x] + sdata[1][threadIdx.x] +
                  sdata[2][threadIdx.x] + sdata[3][threadIdx.x];
        partials[threadIdx.x * nblocks + blockIdx.x] = s;
    }
}

__global__ __launch_bounds__(256) void reduce_pool_kernel(const float* __restrict__ partials,
                                                          int nblocks,
                                                          float* __restrict__ pooled) {
    int f = blockIdx.x;
    const float* col = partials + (size_t)f * nblocks;
    float s = 0.f;
    for (int i = threadIdx.x; i < nblocks; i += 256) s += col[i];
    __shared__ float red[256];
    red[threadIdx.x] = s;
    __syncthreads();
    for (int ofs = 128; ofs > 0; ofs >>= 1) {
        if (threadIdx.x < ofs) red[threadIdx.x] += red[threadIdx.x + ofs];
        __syncthreads();
    }
    if (threadIdx.x == 0) pooled[f] = red[0];
}

__global__ __launch_bounds__(64) void final_kernel(const float* __restrict__ pooled,
                                                   const float* __restrict__ fcw,
                                                   const float* __restrict__ fcb,
                                                   float* __restrict__ out, int n) {
    if (threadIdx.x == 0) {
        double s = 0.0;
        for (int j = 0; j < F2; ++j) s += ((double)pooled[j] / (double)n) * (double)fcw[j];
        out[0] = (float)(s + (double)fcb[0]);
    }
}

// ---------------- launch ----------------

extern "C" void kernel_launch(void* const* d_in, const int* in_sizes, int n_in,
                              void* d_out, int out_size, void* d_ws, size_t ws_size,
                              hipStream_t stream) {
    const float* x   = (const float*)d_in[0];
    const int*   ei  = (const int*)d_in[1];
    const float* W1  = (const float*)d_in[2];
    const float* b1  = (const float*)d_in[3];
    const float* W2  = (const float*)d_in[4];
    const float* b2  = (const float*)d_in[5];
    const float* fcw = (const float*)d_in[6];
    const float* fcb = (const float*)d_in[7];
    float* out = (float*)d_out;

    const int N = in_sizes[0] / 256;  // 100000
    const int E = in_sizes[1] / 2;    // 3200000
    const int K1 = in_sizes[2] / F1;  // 256
    const int* src = ei;
    const int* dst = ei + E;

    const int NB = (N + BNODES - 1) >> BSH;  // 782 buckets
    const int SC = NB * NBLK;                // hist entries
    const int CH = (E + NBLK - 1) / NBLK;    // edges per hist/scatter block
    const int nb2 = (N + 3) / 4;             // agg2 blocks (4 nodes/block)

    char* ws = (char*)d_ws;
    size_t off = 0;
    auto alloc = [&](size_t bytes) -> void* {
        void* p = ws + off;
        off = (off + bytes + 255) & ~(size_t)255;
        return p;
    };
    int SCcap = SC > N ? SC : N;
    int*   tmp      = (int*)alloc((size_t)SCcap * 4);
    int*   bsums    = (int*)alloc(2048);
    int*   bscan    = (int*)alloc(2048);
    int*   row_off  = (int*)alloc((size_t)N * 4);
    int*   deg      = (int*)alloc((size_t)N * 4);
    float* dinv     = (float*)alloc((size_t)N * 4);
    int*   csr      = (int*)alloc((size_t)E * 4);
    // region P: buck (E int) aliases g1 (N*F1 halves) — buck dead before gemm1 writes g1
    size_t szP = (size_t)E * 4;
    size_t szG1 = (size_t)N * F1 * 2;
    void* P = alloc(szP > szG1 ? szP : szG1);
    int*    buck = (int*)P;
    __half* g1   = (__half*)P;
    // region Q: hist_T+hscan alias h1 — hist dead before agg1 writes h1
    size_t szH = 2 * ((((size_t)SC * 4) + 255) & ~(size_t)255);
    size_t szH1 = (size_t)N * F1 * 4;
    void* Q = alloc(szH > szH1 ? szH : szH1);
    int* hist_T = (int*)Q;
    int* hscan  = (int*)((char*)Q + ((((size_t)SC * 4) + 255) & ~(size_t)255));
    float* h1   = (float*)Q;
    __half* g2      = (__half*)alloc((size_t)N * F2 * 2);
    float* partials = (float*)alloc((size_t)F2 * nb2 * 4);
    float* pooled   = (float*)alloc(F2 * 4);

    // ---- CSR build via counting sort (no global atomics, dense writes) ----
    bucket_hist_kernel<<<NBLK, 256, 0, stream>>>(dst, hist_T, E, CH, NB);
    int nbS = (SC + 1023) / 1024;
    scan_blocks_kernel<<<nbS, 256, 0, stream>>>(hist_T, tmp, bsums, SC);
    scan_sums_kernel<<<1, 512, 0, stream>>>(bsums, bscan, nbS);
    scan_add_kernel<<<(SC + 255) / 256, 256, 0, stream>>>(tmp, bscan, hscan, SC);
    bucket_scatter_kernel<<<NBLK, 256, 0, stream>>>(src, dst, hscan, buck, E, CH, NB);
    bucket_deg_kernel<<<NB, 256, 0, stream>>>(buck, hscan, deg, dinv, E, N, NB);
    int nbS2 = (N + 1023) / 1024;
    scan_blocks_kernel<<<nbS2, 256, 0, stream>>>(deg, tmp, bsums, N);
    scan_sums_kernel<<<1, 512, 0, stream>>>(bsums, bscan, nbS2);
    scan_add_kernel<<<(N + 255) / 256, 256, 0, stream>>>(tmp, bscan, row_off, N);
    bucket_fill_kernel<<<NB, 256, 0, stream>>>(buck, hscan, row_off, csr, E, N, NB);

    // ---- layer 1: g1 = half((x @ W1) * dinv) ----
    gemm_scale_kernel<128, 64, 32, 8, 4><<<(N + 127) / 128, 256, 0, stream>>>(x, W1, dinv, g1, N, K1, F1);
    agg1_kernel<<<(N + 3) / 4, 256, 0, stream>>>(g1, row_off, deg, csr, dinv, b1, h1, N);

    // ---- layer 2: g2 = half((h1 @ W2) * dinv) ----
    gemm_scale_kernel<128, 32, 32, 8, 2><<<(N + 127) / 128, 256, 0, stream>>>(h1, W2, dinv, g2, N, F1, F2);
    agg2_pool_kernel<<<nb2, 256, 0, stream>>>(g2, row_off, deg, csr, dinv, b2, partials, nb2, N);

    reduce_pool_kernel<<<F2, 256, 0, stream>>>(partials, nb2, pooled);
    final_kernel<<<1, 64, 0, stream>>>(pooled, fcw, fcb, out, N);
}

// Round 7
// 264.038 us; speedup vs baseline: 3.1525x; 1.1530x over previous
//
#include <hip/hip_runtime.h>
#include <hip/hip_fp16.h>

#ifndef F1
#define F1 64
#define F2 32
#endif

#define NBLK 512     // blocks for bucket hist/scatter passes
#define BSH  7       // bucket = dst >> 7  (128 nodes per bucket)
#define BNODES 128

typedef _Float16 half8 __attribute__((ext_vector_type(8)));
typedef float floatx4 __attribute__((ext_vector_type(4)));

// ---------------- scans (generic) ----------------
__global__ __launch_bounds__(256) void scan_blocks_kernel(const int* __restrict__ in,
                                                          int* __restrict__ tmp,
                                                          int* __restrict__ blk_sums, int n) {
    __shared__ int sdata[256];
    int t = threadIdx.x;
    int base = blockIdx.x * 1024 + t * 4;
    int v[4];
#pragma unroll
    for (int j = 0; j < 4; ++j) v[j] = (base + j < n) ? in[base + j] : 0;
    int mysum = v[0] + v[1] + v[2] + v[3];
    sdata[t] = mysum;
    __syncthreads();
    for (int ofs = 1; ofs < 256; ofs <<= 1) {
        int val = (t >= ofs) ? sdata[t - ofs] : 0;
        __syncthreads();
        sdata[t] += val;
        __syncthreads();
    }
    int incl = sdata[t];
    int excl = incl - mysum;
    if (t == 255) blk_sums[blockIdx.x] = incl;
    int run = excl;
#pragma unroll
    for (int j = 0; j < 4; ++j) {
        if (base + j < n) tmp[base + j] = run;
        run += v[j];
    }
}

__global__ __launch_bounds__(512) void scan_sums_kernel(const int* __restrict__ blk_sums,
                                                        int* __restrict__ blk_scanned, int nb) {
    __shared__ int sdata[512];
    int t = threadIdx.x;
    int mine = (t < nb) ? blk_sums[t] : 0;
    sdata[t] = mine;
    __syncthreads();
    for (int ofs = 1; ofs < 512; ofs <<= 1) {
        int val = (t >= ofs) ? sdata[t - ofs] : 0;
        __syncthreads();
        sdata[t] += val;
        __syncthreads();
    }
    blk_scanned[t] = sdata[t] - mine;  // exclusive
}

__global__ __launch_bounds__(256) void scan_add_kernel(const int* __restrict__ tmp,
                                                       const int* __restrict__ blk_scanned,
                                                       int* __restrict__ out, int n) {
    int i = blockIdx.x * 256 + threadIdx.x;
    if (i < n) out[i] = tmp[i] + blk_scanned[i >> 10];
}

// ---------------- bucket passes (counting sort by dst>>BSH) ----------------

__global__ __launch_bounds__(256) void bucket_hist_kernel(const int* __restrict__ dst,
                                                          int* __restrict__ hist_T,
                                                          int E, int CH, int NB) {
    __shared__ int lh[1024];
    int b = blockIdx.x;
    for (int i = threadIdx.x; i < NB; i += 256) lh[i] = 0;
    __syncthreads();
    int start = b * CH, end = min(E, start + CH);
    for (int e = start + threadIdx.x; e < end; e += 256)
        atomicAdd(&lh[dst[e] >> BSH], 1);
    __syncthreads();
    for (int k = threadIdx.x; k < NB; k += 256)
        hist_T[k * NBLK + b] = lh[k];
}

// Scatter packed (src<<7)|(dst&127) into contiguous bucket regions.
__global__ __launch_bounds__(256) void bucket_scatter_kernel(const int* __restrict__ src,
                                                             const int* __restrict__ dst,
                                                             const int* __restrict__ hscan,
                                                             int* __restrict__ buck,
                                                             int E, int CH, int NB) {
    __shared__ int cur[1024];
    int b = blockIdx.x;
    for (int i = threadIdx.x; i < NB; i += 256) cur[i] = hscan[i * NBLK + b];
    __syncthreads();
    int start = b * CH, end = min(E, start + CH);
    for (int e = start + threadIdx.x; e < end; e += 256) {
        int d = dst[e];
        int pos = atomicAdd(&cur[d >> BSH], 1);
        buck[pos] = (src[e] << BSH) | (d & (BNODES - 1));
    }
}

__global__ __launch_bounds__(256) void bucket_deg_kernel(const int* __restrict__ buck,
                                                         const int* __restrict__ hscan,
                                                         int* __restrict__ deg,
                                                         float* __restrict__ dinv,
                                                         int E, int N, int NB) {
    __shared__ int cnt[BNODES];
    int k = blockIdx.x;
    if (threadIdx.x < BNODES) cnt[threadIdx.x] = 0;
    __syncthreads();
    int bs = hscan[k * NBLK];
    int be = (k + 1 < NB) ? hscan[(k + 1) * NBLK] : E;
    for (int e = bs + threadIdx.x; e < be; e += 256)
        atomicAdd(&cnt[buck[e] & (BNODES - 1)], 1);
    __syncthreads();
    int node0 = k << BSH;
    int i = node0 + threadIdx.x;
    if (threadIdx.x < BNODES && i < N) {
        int c = cnt[threadIdx.x];
        deg[i] = c;
        dinv[i] = rsqrtf((float)(c + 1));  // +1 self loop
    }
}

__global__ __launch_bounds__(256) void bucket_fill_kernel(const int* __restrict__ buck,
                                                          const int* __restrict__ hscan,
                                                          const int* __restrict__ row_off,
                                                          int* __restrict__ csr,
                                                          int E, int N, int NB) {
    __shared__ int lrow[BNODES];
    __shared__ int lcur[BNODES];
    int k = blockIdx.x;
    int node0 = k << BSH;
    if (threadIdx.x < BNODES) {
        lcur[threadIdx.x] = 0;
        int i = node0 + threadIdx.x;
        lrow[threadIdx.x] = (i < N) ? row_off[i] : 0;
    }
    __syncthreads();
    int bs = hscan[k * NBLK];
    int be = (k + 1 < NB) ? hscan[(k + 1) * NBLK] : E;
    for (int e = bs + threadIdx.x; e < be; e += 256) {
        int p = buck[e];
        int li = p & (BNODES - 1);
        int pos = lrow[li] + atomicAdd(&lcur[li], 1);
        csr[pos] = p >> BSH;
    }
}

// ---------------- W pre-transpose to fp16: Wt[n][k] = W[k][n] ----------------

__global__ __launch_bounds__(256) void prep_w_kernel(const float* __restrict__ W1,
                                                     const float* __restrict__ W2,
                                                     __half* __restrict__ W1t,
                                                     __half* __restrict__ W2t) {
    int t = blockIdx.x * 256 + threadIdx.x;
    int stride = gridDim.x * 256;
    for (int e = t; e < 64 * 256; e += stride) {
        int n = e >> 8, k = e & 255;
        W1t[e] = __float2half(W1[k * 64 + n]);
    }
    for (int e = t; e < 32 * 64; e += stride) {
        int n = e >> 6, k = e & 63;
        W2t[e] = __float2half(W2[k * 32 + n]);
    }
}

// ---------------- MFMA GEMM: C = half((A @ B) * dinv[row]) ----------------
// BM=64 (4 waves x 16-row tile), BK=32, BN = 64 or 32. A: [M][K] (f32 or fp16),
// Bt: [BN][K] fp16 (pre-transposed). LDS tiles quad-XOR swizzled: both the
// staged half8 writes and the ds_read_b128 fragment reads are conflict-free.

__device__ __forceinline__ int swz(int p, int r) { return (p ^ ((r >> 1) & 3)) << 4; }

template <bool AF32, int K, int BN>
__global__ __launch_bounds__(256) void gemm_mfma_kernel(const void* __restrict__ Aptr,
                                                        const __half* __restrict__ Bt,
                                                        const float* __restrict__ dinv,
                                                        __half* __restrict__ C,
                                                        int M) {
    constexpr int NT = BN / 16;
    __shared__ half8 Ash[64 * 4];   // 64 rows x 64B
    __shared__ half8 Bsh[BN * 4];   // BN cols x 64B
    char* Ab = (char*)Ash;
    char* Bb = (char*)Bsh;
    int tid = threadIdx.x;
    int w = tid >> 6;        // wave -> row tile
    int l = tid & 63;
    int row0 = blockIdx.x * 64;
    int sr = tid >> 2, sp = tid & 3;   // staging row / k-plane
    int fr = l & 15, fp = l >> 4;      // fragment row(col) / k-plane
    int arow = w * 16 + fr;
    int a_off = arow * 64 + swz(fp, arow);

    floatx4 acc[NT];
#pragma unroll
    for (int c = 0; c < NT; ++c) acc[c] = (floatx4){0.f, 0.f, 0.f, 0.f};

    for (int k0 = 0; k0 < K; k0 += 32) {
        // stage A (f32->fp16 cvt in regs; rows beyond M zero-filled)
        half8 av = {};
        int gr = row0 + sr;
        if (gr < M) {
            if constexpr (AF32) {
                const float* A = (const float*)Aptr;
                float4 f0 = *(const float4*)(A + (size_t)gr * K + k0 + sp * 8);
                float4 f1 = *(const float4*)(A + (size_t)gr * K + k0 + sp * 8 + 4);
                av[0] = (_Float16)f0.x; av[1] = (_Float16)f0.y;
                av[2] = (_Float16)f0.z; av[3] = (_Float16)f0.w;
                av[4] = (_Float16)f1.x; av[5] = (_Float16)f1.y;
                av[6] = (_Float16)f1.z; av[7] = (_Float16)f1.w;
            } else {
                const __half* A = (const __half*)Aptr;
                av = *(const half8*)(A + (size_t)gr * K + k0 + sp * 8);
            }
        }
        *(half8*)(Ab + sr * 64 + swz(sp, sr)) = av;
        // stage B
        if (tid < BN * 4) {
            int n = tid >> 2, p = tid & 3;
            half8 bv = *(const half8*)(Bt + (size_t)n * K + k0 + p * 8);
            *(half8*)(Bb + n * 64 + swz(p, n)) = bv;
        }
        __syncthreads();
        half8 a = *(const half8*)(Ab + a_off);
#pragma unroll
        for (int c = 0; c < NT; ++c) {
            int col = c * 16 + fr;
            half8 b = *(const half8*)(Bb + col * 64 + swz(fp, col));
            acc[c] = __builtin_amdgcn_mfma_f32_16x16x32_f16(a, b, acc[c], 0, 0, 0);
        }
        __syncthreads();
    }
    // epilogue: D row=(l>>4)*4+i, col=c*16+(l&15)
#pragma unroll
    for (int i = 0; i < 4; ++i) {
        int r = row0 + w * 16 + fp * 4 + i;
        if (r < M) {
            float dn = dinv[r];
#pragma unroll
            for (int c = 0; c < NT; ++c)
                C[(size_t)r * BN + c * 16 + fr] = __float2half(acc[c][i] * dn);
        }
    }
}

// ---------------- gather helpers ----------------

__device__ __forceinline__ void acc_row8(const __half* __restrict__ base,
                                         float& a0, float& a1, float& a2, float& a3) {
    uint2 raw = *reinterpret_cast<const uint2*>(base);
    __half2 h01 = *reinterpret_cast<const __half2*>(&raw.x);
    __half2 h23 = *reinterpret_cast<const __half2*>(&raw.y);
    float2 f01 = __half22float2(h01);
    float2 f23 = __half22float2(h23);
    a0 += f01.x; a1 += f01.y; a2 += f23.x; a3 += f23.y;
}

// ---------------- Aggregation layer 1: wave per node ----------------
// 64 lanes = 4 edge-groups x 16 feature-quads; h1 output fp16.

__global__ __launch_bounds__(256) void agg1_kernel(const __half* __restrict__ g1,
                                                   const int* __restrict__ row_off,
                                                   const int* __restrict__ deg,
                                                   const int* __restrict__ csr,
                                                   const float* __restrict__ dinv,
                                                   const float* __restrict__ b1,
                                                   __half* __restrict__ h1, int n) {
    int node = (blockIdx.x * 256 + threadIdx.x) >> 6;
    int lane = threadIdx.x & 63;
    int g = lane >> 4;        // edge group 0..3
    int f4 = lane & 15;       // feature quad 0..15
    if (node >= n) return;
    int start = row_off[node];
    int end = start + deg[node];
    float a0 = 0.f, a1 = 0.f, a2 = 0.f, a3 = 0.f;
    if (g == 0)  // self loop counted once
        acc_row8(g1 + ((size_t)node << 6) + f4 * 4, a0, a1, a2, a3);
    int e = start;
    for (; e + 16 <= end; e += 16) {
        int s0 = csr[e + g];
        int s1 = csr[e + 4 + g];
        int s2 = csr[e + 8 + g];
        int s3 = csr[e + 12 + g];
        acc_row8(g1 + ((size_t)s0 << 6) + f4 * 4, a0, a1, a2, a3);
        acc_row8(g1 + ((size_t)s1 << 6) + f4 * 4, a0, a1, a2, a3);
        acc_row8(g1 + ((size_t)s2 << 6) + f4 * 4, a0, a1, a2, a3);
        acc_row8(g1 + ((size_t)s3 << 6) + f4 * 4, a0, a1, a2, a3);
    }
    for (; e + 4 <= end; e += 4) {
        int s = csr[e + g];
        acc_row8(g1 + ((size_t)s << 6) + f4 * 4, a0, a1, a2, a3);
    }
    if (e + g < end) {
        int s = csr[e + g];
        acc_row8(g1 + ((size_t)s << 6) + f4 * 4, a0, a1, a2, a3);
    }
    a0 += __shfl_xor(a0, 16); a1 += __shfl_xor(a1, 16);
    a2 += __shfl_xor(a2, 16); a3 += __shfl_xor(a3, 16);
    a0 += __shfl_xor(a0, 32); a1 += __shfl_xor(a1, 32);
    a2 += __shfl_xor(a2, 32); a3 += __shfl_xor(a3, 32);
    if (g == 0) {
        float dn = dinv[node];
        float4 bias = *reinterpret_cast<const float4*>(b1 + f4 * 4);
        __half hh[4];
        hh[0] = __float2half(fmaxf(a0 * dn + bias.x, 0.f));
        hh[1] = __float2half(fmaxf(a1 * dn + bias.y, 0.f));
        hh[2] = __float2half(fmaxf(a2 * dn + bias.z, 0.f));
        hh[3] = __float2half(fmaxf(a3 * dn + bias.w, 0.f));
        *reinterpret_cast<uint2*>(h1 + ((size_t)node << 6) + f4 * 4) =
            *reinterpret_cast<const uint2*>(hh);
    }
}

// ---------------- Aggregation layer 2 + pooling: wave per node ----------------

__global__ __launch_bounds__(256) void agg2_pool_kernel(const __half* __restrict__ g2,
                                                        const int* __restrict__ row_off,
                                                        const int* __restrict__ deg,
                                                        const int* __restrict__ csr,
                                                        const float* __restrict__ dinv,
                                                        const float* __restrict__ b2,
                                                        float* __restrict__ partials,
                                                        int nblocks, int n) {
    int node = (blockIdx.x * 256 + threadIdx.x) >> 6;
    int w = (threadIdx.x >> 6) & 3;  // wave in block
    int lane = threadIdx.x & 63;
    int g = lane >> 3;       // edge group 0..7
    int f4 = lane & 7;       // feature quad 0..7
    float a0 = 0.f, a1 = 0.f, a2 = 0.f, a3 = 0.f;
    if (node < n) {
        int start = row_off[node];
        int end = start + deg[node];
        if (g == 0)
            acc_row8(g2 + ((size_t)node << 5) + f4 * 4, a0, a1, a2, a3);
        int e = start;
        for (; e + 16 <= end; e += 16) {
            int s0 = csr[e + g];
            int s1 = csr[e + 8 + g];
            acc_row8(g2 + ((size_t)s0 << 5) + f4 * 4, a0, a1, a2, a3);
            acc_row8(g2 + ((size_t)s1 << 5) + f4 * 4, a0, a1, a2, a3);
        }
        for (; e + 8 <= end; e += 8) {
            int s = csr[e + g];
            acc_row8(g2 + ((size_t)s << 5) + f4 * 4, a0, a1, a2, a3);
        }
        if (e + g < end) {
            int s = csr[e + g];
            acc_row8(g2 + ((size_t)s << 5) + f4 * 4, a0, a1, a2, a3);
        }
        a0 += __shfl_xor(a0, 8);  a1 += __shfl_xor(a1, 8);
        a2 += __shfl_xor(a2, 8);  a3 += __shfl_xor(a3, 8);
        a0 += __shfl_xor(a0, 16); a1 += __shfl_xor(a1, 16);
        a2 += __shfl_xor(a2, 16); a3 += __shfl_xor(a3, 16);
        a0 += __shfl_xor(a0, 32); a1 += __shfl_xor(a1, 32);
        a2 += __shfl_xor(a2, 32); a3 += __shfl_xor(a3, 32);
    }
    __shared__ float sdata[4][32];
    if (g == 0) {
        float4 o = make_float4(0.f, 0.f, 0.f, 0.f);
        if (node < n) {
            float dn = dinv[node];
            float4 bias = *reinterpret_cast<const float4*>(b2 + f4 * 4);
            o.x = fmaxf(a0 * dn + bias.x, 0.f);
            o.y = fmaxf(a1 * dn + bias.y, 0.f);
            o.z = fmaxf(a2 * dn + bias.z, 0.f);
            o.w = fmaxf(a3 * dn + bias.w, 0.f);
        }
        *reinterpret_cast<float4*>(&sdata[w][f4 * 4]) = o;
    }
    __syncthreads();
    if (threadIdx.x < 32) {
        float s = sdata[0][threadIdx.x] + sdata[1][threadIdx.x] +
                  sdata[2][threadIdx.x] + sdata[3][threadIdx.x];
        partials[threadIdx.x * nblocks + blockIdx.x] = s;
    }
}

__global__ __launch_bounds__(256) void reduce_pool_kernel(const float* __restrict__ partials,
                                                          int nblocks,
                                                          float* __restrict__ pooled) {
    int f = blockIdx.x;
    const float* col = partials + (size_t)f * nblocks;
    float s = 0.f;
    for (int i = threadIdx.x; i < nblocks; i += 256) s += col[i];
    __shared__ float red[256];
    red[threadIdx.x] = s;
    __syncthreads();
    for (int ofs = 128; ofs > 0; ofs >>= 1) {
        if (threadIdx.x < ofs) red[threadIdx.x] += red[threadIdx.x + ofs];
        __syncthreads();
    }
    if (threadIdx.x == 0) pooled[f] = red[0];
}

__global__ __launch_bounds__(64) void final_kernel(const float* __restrict__ pooled,
                                                   const float* __restrict__ fcw,
                                                   const float* __restrict__ fcb,
                                                   float* __restrict__ out, int n) {
    if (threadIdx.x == 0) {
        double s = 0.0;
        for (int j = 0; j < F2; ++j) s += ((double)pooled[j] / (double)n) * (double)fcw[j];
        out[0] = (float)(s + (double)fcb[0]);
    }
}

// ---------------- launch ----------------

extern "C" void kernel_launch(void* const* d_in, const int* in_sizes, int n_in,
                              void* d_out, int out_size, void* d_ws, size_t ws_size,
                              hipStream_t stream) {
    const float* x   = (const float*)d_in[0];
    const int*   ei  = (const int*)d_in[1];
    const float* W1  = (const float*)d_in[2];
    const float* b1  = (const float*)d_in[3];
    const float* W2  = (const float*)d_in[4];
    const float* b2  = (const float*)d_in[5];
    const float* fcw = (const float*)d_in[6];
    const float* fcb = (const float*)d_in[7];
    float* out = (float*)d_out;

    const int N = in_sizes[0] / 256;  // 100000
    const int E = in_sizes[1] / 2;    // 3200000
    const int* src = ei;
    const int* dst = ei + E;

    const int NB = (N + BNODES - 1) >> BSH;  // 782 buckets
    const int SC = NB * NBLK;                // hist entries
    const int CH = (E + NBLK - 1) / NBLK;    // edges per hist/scatter block
    const int nb2 = (N + 3) / 4;             // agg2 blocks (4 nodes/block)

    char* ws = (char*)d_ws;
    size_t off = 0;
    auto alloc = [&](size_t bytes) -> void* {
        void* p = ws + off;
        off = (off + bytes + 255) & ~(size_t)255;
        return p;
    };
    int SCcap = SC > N ? SC : N;
    int*   tmp      = (int*)alloc((size_t)SCcap * 4);
    int*   bsums    = (int*)alloc(2048);
    int*   bscan    = (int*)alloc(2048);
    int*   row_off  = (int*)alloc((size_t)N * 4);
    int*   deg      = (int*)alloc((size_t)N * 4);
    float* dinv     = (float*)alloc((size_t)N * 4);
    int*   csr      = (int*)alloc((size_t)E * 4);
    __half* W1t     = (__half*)alloc((size_t)64 * 256 * 2);
    __half* W2t     = (__half*)alloc((size_t)32 * 64 * 2);
    // region P: buck (E int) aliases g1 (N*F1 halves) — buck dead before gemm1 writes g1
    size_t szP = (size_t)E * 4;
    size_t szG1 = (size_t)N * F1 * 2;
    void* P = alloc(szP > szG1 ? szP : szG1);
    int*    buck = (int*)P;
    __half* g1   = (__half*)P;
    // region Q: hist_T+hscan alias h1 (fp16 now) — hist dead before agg1 writes h1
    size_t szHa = ((((size_t)SC * 4) + 255) & ~(size_t)255);
    size_t szH = 2 * szHa;
    size_t szH1 = (size_t)N * F1 * 2;
    void* Q = alloc(szH > szH1 ? szH : szH1);
    int* hist_T = (int*)Q;
    int* hscan  = (int*)((char*)Q + szHa);
    __half* h1  = (__half*)Q;
    __half* g2      = (__half*)alloc((size_t)N * F2 * 2);
    float* partials = (float*)alloc((size_t)F2 * nb2 * 4);
    float* pooled   = (float*)alloc(F2 * 4);

    // ---- weight prep (independent of CSR chain) ----
    prep_w_kernel<<<32, 256, 0, stream>>>(W1, W2, W1t, W2t);

    // ---- CSR build via counting sort (no global atomics, dense writes) ----
    bucket_hist_kernel<<<NBLK, 256, 0, stream>>>(dst, hist_T, E, CH, NB);
    int nbS = (SC + 1023) / 1024;
    scan_blocks_kernel<<<nbS, 256, 0, stream>>>(hist_T, tmp, bsums, SC);
    scan_sums_kernel<<<1, 512, 0, stream>>>(bsums, bscan, nbS);
    scan_add_kernel<<<(SC + 255) / 256, 256, 0, stream>>>(tmp, bscan, hscan, SC);
    bucket_scatter_kernel<<<NBLK, 256, 0, stream>>>(src, dst, hscan, buck, E, CH, NB);
    bucket_deg_kernel<<<NB, 256, 0, stream>>>(buck, hscan, deg, dinv, E, N, NB);
    int nbS2 = (N + 1023) / 1024;
    scan_blocks_kernel<<<nbS2, 256, 0, stream>>>(deg, tmp, bsums, N);
    scan_sums_kernel<<<1, 512, 0, stream>>>(bsums, bscan, nbS2);
    scan_add_kernel<<<(N + 255) / 256, 256, 0, stream>>>(tmp, bscan, row_off, N);
    bucket_fill_kernel<<<NB, 256, 0, stream>>>(buck, hscan, row_off, csr, E, N, NB);

    int nbG = (N + 63) / 64;  // 1563
    // ---- layer 1: g1 = half((x @ W1) * dinv) via MFMA ----
    gemm_mfma_kernel<true, 256, 64><<<nbG, 256, 0, stream>>>(x, W1t, dinv, g1, N);
    agg1_kernel<<<(N + 3) / 4, 256, 0, stream>>>(g1, row_off, deg, csr, dinv, b1, h1, N);

    // ---- layer 2: g2 = half((h1 @ W2) * dinv) via MFMA ----
    gemm_mfma_kernel<false, 64, 32><<<nbG, 256, 0, stream>>>(h1, W2t, dinv, g2, N);
    agg2_pool_kernel<<<nb2, 256, 0, stream>>>(g2, row_off, deg, csr, dinv, b2, partials, nb2, N);

    reduce_pool_kernel<<<F2, 256, 0, stream>>>(partials, nb2, pooled);
    final_kernel<<<1, 64, 0, stream>>>(pooled, fcw, fcb, out, N);
}

// Round 8
// 249.914 us; speedup vs baseline: 3.3306x; 1.0565x over previous
//
#include <hip/hip_runtime.h>
#include <hip/hip_fp16.h>

#ifndef F1
#define F1 64
#define F2 32
#endif

#define NBLK 512     // blocks for bucket hist/scatter passes
#define BSH  7       // bucket = dst >> 7  (128 nodes per bucket)
#define BNODES 128

typedef _Float16 half8 __attribute__((ext_vector_type(8)));
typedef float floatx4 __attribute__((ext_vector_type(4)));

// ---------------- scans ----------------
// exclusive scan, 1024 elems/block (256 thr x 4). Final add is fused into consumers.
__global__ __launch_bounds__(256) void scan_blocks_kernel(const int* __restrict__ in,
                                                          int* __restrict__ tmp,
                                                          int* __restrict__ blk_sums, int n) {
    __shared__ int sdata[256];
    int t = threadIdx.x;
    int base = blockIdx.x * 1024 + t * 4;
    int v[4];
#pragma unroll
    for (int j = 0; j < 4; ++j) v[j] = (base + j < n) ? in[base + j] : 0;
    int mysum = v[0] + v[1] + v[2] + v[3];
    sdata[t] = mysum;
    __syncthreads();
    for (int ofs = 1; ofs < 256; ofs <<= 1) {
        int val = (t >= ofs) ? sdata[t - ofs] : 0;
        __syncthreads();
        sdata[t] += val;
        __syncthreads();
    }
    int incl = sdata[t];
    int excl = incl - mysum;
    if (t == 255) blk_sums[blockIdx.x] = incl;
    int run = excl;
#pragma unroll
    for (int j = 0; j < 4; ++j) {
        if (base + j < n) tmp[base + j] = run;
        run += v[j];
    }
}

__global__ __launch_bounds__(512) void scan_sums_kernel(const int* __restrict__ blk_sums,
                                                        int* __restrict__ blk_scanned, int nb) {
    __shared__ int sdata[512];
    int t = threadIdx.x;
    int mine = (t < nb) ? blk_sums[t] : 0;
    sdata[t] = mine;
    __syncthreads();
    for (int ofs = 1; ofs < 512; ofs <<= 1) {
        int val = (t >= ofs) ? sdata[t - ofs] : 0;
        __syncthreads();
        sdata[t] += val;
        __syncthreads();
    }
    blk_scanned[t] = sdata[t] - mine;  // exclusive
}

// ---------------- bucket passes (counting sort by dst>>BSH) ----------------
// Block NBLK additionally does weight prep (fused to save a dispatch).

__global__ __launch_bounds__(256) void bucket_hist_prep_kernel(const int* __restrict__ dst,
                                                               int* __restrict__ hist_T,
                                                               const float* __restrict__ W1,
                                                               const float* __restrict__ W2,
                                                               __half* __restrict__ W1t,
                                                               __half* __restrict__ W2t,
                                                               int E, int CH, int NB) {
    int b = blockIdx.x;
    if (b == NBLK) {  // weight prep: Wt[n][k] = half(W[k][n])
        for (int e = threadIdx.x; e < 64 * 256; e += 256) {
            int n = e >> 8, k = e & 255;
            W1t[e] = __float2half(W1[k * 64 + n]);
        }
        for (int e = threadIdx.x; e < 32 * 64; e += 256) {
            int n = e >> 6, k = e & 63;
            W2t[e] = __float2half(W2[k * 32 + n]);
        }
        return;
    }
    __shared__ int lh[1024];
    for (int i = threadIdx.x; i < NB; i += 256) lh[i] = 0;
    __syncthreads();
    int start = b * CH, end = min(E, start + CH);
    for (int e0 = start + threadIdx.x * 4; e0 < end; e0 += 1024) {
        if (e0 + 4 <= end) {
            int4 d4 = *reinterpret_cast<const int4*>(dst + e0);
            atomicAdd(&lh[d4.x >> BSH], 1);
            atomicAdd(&lh[d4.y >> BSH], 1);
            atomicAdd(&lh[d4.z >> BSH], 1);
            atomicAdd(&lh[d4.w >> BSH], 1);
        } else {
            for (int e = e0; e < end; ++e) atomicAdd(&lh[dst[e] >> BSH], 1);
        }
    }
    __syncthreads();
    for (int k = threadIdx.x; k < NB; k += 256)
        hist_T[k * NBLK + b] = lh[k];
}

// Scatter packed (src<<7)|(dst&127) into contiguous bucket regions.
// Offsets read as tmp[idx]+bscan[idx>>10] (scan_add fused).
__global__ __launch_bounds__(256) void bucket_scatter_kernel(const int* __restrict__ src,
                                                             const int* __restrict__ dst,
                                                             const int* __restrict__ tmp,
                                                             const int* __restrict__ bscan,
                                                             int* __restrict__ buck,
                                                             int E, int CH, int NB) {
    __shared__ int cur[1024];
    int b = blockIdx.x;
    for (int i = threadIdx.x; i < NB; i += 256) {
        int idx = i * NBLK + b;
        cur[i] = tmp[idx] + bscan[idx >> 10];
    }
    __syncthreads();
    int start = b * CH, end = min(E, start + CH);
    for (int e0 = start + threadIdx.x * 4; e0 < end; e0 += 1024) {
        if (e0 + 4 <= end) {
            int4 s4 = *reinterpret_cast<const int4*>(src + e0);
            int4 d4 = *reinterpret_cast<const int4*>(dst + e0);
            int p0 = atomicAdd(&cur[d4.x >> BSH], 1);
            buck[p0] = (s4.x << BSH) | (d4.x & (BNODES - 1));
            int p1 = atomicAdd(&cur[d4.y >> BSH], 1);
            buck[p1] = (s4.y << BSH) | (d4.y & (BNODES - 1));
            int p2 = atomicAdd(&cur[d4.z >> BSH], 1);
            buck[p2] = (s4.z << BSH) | (d4.z & (BNODES - 1));
            int p3 = atomicAdd(&cur[d4.w >> BSH], 1);
            buck[p3] = (s4.w << BSH) | (d4.w & (BNODES - 1));
        } else {
            for (int e = e0; e < end; ++e) {
                int d = dst[e];
                int pos = atomicAdd(&cur[d >> BSH], 1);
                buck[pos] = (src[e] << BSH) | (d & (BNODES - 1));
            }
        }
    }
}

__global__ __launch_bounds__(256) void bucket_deg_kernel(const int* __restrict__ buck,
                                                         const int* __restrict__ tmp,
                                                         const int* __restrict__ bscan,
                                                         int* __restrict__ deg,
                                                         float* __restrict__ dinv,
                                                         int E, int N, int NB) {
    __shared__ int cnt[BNODES];
    int k = blockIdx.x;
    if (threadIdx.x < BNODES) cnt[threadIdx.x] = 0;
    __syncthreads();
    int i0 = k * NBLK;
    int bs = tmp[i0] + bscan[i0 >> 10];
    int be = E;
    if (k + 1 < NB) {
        int i1 = (k + 1) * NBLK;
        be = tmp[i1] + bscan[i1 >> 10];
    }
    for (int e = bs + threadIdx.x; e < be; e += 256)
        atomicAdd(&cnt[buck[e] & (BNODES - 1)], 1);
    __syncthreads();
    int node0 = k << BSH;
    int i = node0 + threadIdx.x;
    if (threadIdx.x < BNODES && i < N) {
        int c = cnt[threadIdx.x];
        deg[i] = c;
        dinv[i] = rsqrtf((float)(c + 1));  // +1 self loop
    }
}

__global__ __launch_bounds__(256) void bucket_fill_kernel(const int* __restrict__ buck,
                                                          const int* __restrict__ tmp,
                                                          const int* __restrict__ bscan,
                                                          const int* __restrict__ tmpB,
                                                          const int* __restrict__ bscanB,
                                                          int* __restrict__ csr,
                                                          int E, int N, int NB) {
    __shared__ int lrow[BNODES];
    __shared__ int lcur[BNODES];
    int k = blockIdx.x;
    int node0 = k << BSH;
    if (threadIdx.x < BNODES) {
        lcur[threadIdx.x] = 0;
        int i = node0 + threadIdx.x;
        lrow[threadIdx.x] = (i < N) ? (tmpB[i] + bscanB[i >> 10]) : 0;
    }
    __syncthreads();
    int i0 = k * NBLK;
    int bs = tmp[i0] + bscan[i0 >> 10];
    int be = E;
    if (k + 1 < NB) {
        int i1 = (k + 1) * NBLK;
        be = tmp[i1] + bscan[i1 >> 10];
    }
    for (int e = bs + threadIdx.x; e < be; e += 256) {
        int p = buck[e];
        int li = p & (BNODES - 1);
        int pos = lrow[li] + atomicAdd(&lcur[li], 1);
        csr[pos] = p >> BSH;
    }
}

// ---------------- MFMA GEMM: C = half((A @ B) * dinv[row]) ----------------

__device__ __forceinline__ int swz(int p, int r) { return (p ^ ((r >> 1) & 3)) << 4; }

template <bool AF32, int K, int BN>
__global__ __launch_bounds__(256) void gemm_mfma_kernel(const void* __restrict__ Aptr,
                                                        const __half* __restrict__ Bt,
                                                        const float* __restrict__ dinv,
                                                        __half* __restrict__ C,
                                                        int M) {
    constexpr int NT = BN / 16;
    __shared__ half8 Ash[64 * 4];   // 64 rows x 64B
    __shared__ half8 Bsh[BN * 4];   // BN cols x 64B
    char* Ab = (char*)Ash;
    char* Bb = (char*)Bsh;
    int tid = threadIdx.x;
    int w = tid >> 6;
    int l = tid & 63;
    int row0 = blockIdx.x * 64;
    int sr = tid >> 2, sp = tid & 3;   // staging row / k-plane
    int fr = l & 15, fp = l >> 4;      // fragment row(col) / k-plane
    int arow = w * 16 + fr;
    int a_off = arow * 64 + swz(fp, arow);

    floatx4 acc[NT];
#pragma unroll
    for (int c = 0; c < NT; ++c) acc[c] = (floatx4){0.f, 0.f, 0.f, 0.f};

    for (int k0 = 0; k0 < K; k0 += 32) {
        half8 av = {};
        int gr = row0 + sr;
        if (gr < M) {
            if constexpr (AF32) {
                const float* A = (const float*)Aptr;
                float4 f0 = *(const float4*)(A + (size_t)gr * K + k0 + sp * 8);
                float4 f1 = *(const float4*)(A + (size_t)gr * K + k0 + sp * 8 + 4);
                av[0] = (_Float16)f0.x; av[1] = (_Float16)f0.y;
                av[2] = (_Float16)f0.z; av[3] = (_Float16)f0.w;
                av[4] = (_Float16)f1.x; av[5] = (_Float16)f1.y;
                av[6] = (_Float16)f1.z; av[7] = (_Float16)f1.w;
            } else {
                const __half* A = (const __half*)Aptr;
                av = *(const half8*)(A + (size_t)gr * K + k0 + sp * 8);
            }
        }
        *(half8*)(Ab + sr * 64 + swz(sp, sr)) = av;
        if (tid < BN * 4) {
            int n = tid >> 2, p = tid & 3;
            half8 bv = *(const half8*)(Bt + (size_t)n * K + k0 + p * 8);
            *(half8*)(Bb + n * 64 + swz(p, n)) = bv;
        }
        __syncthreads();
        half8 a = *(const half8*)(Ab + a_off);
#pragma unroll
        for (int c = 0; c < NT; ++c) {
            int col = c * 16 + fr;
            half8 b = *(const half8*)(Bb + col * 64 + swz(fp, col));
            acc[c] = __builtin_amdgcn_mfma_f32_16x16x32_f16(a, b, acc[c], 0, 0, 0);
        }
        __syncthreads();
    }
#pragma unroll
    for (int i = 0; i < 4; ++i) {
        int r = row0 + w * 16 + fp * 4 + i;
        if (r < M) {
            float dn = dinv[r];
#pragma unroll
            for (int c = 0; c < NT; ++c)
                C[(size_t)r * BN + c * 16 + fr] = __float2half(acc[c][i] * dn);
        }
    }
}

// ---------------- gather helper: 16B (8 halves) per lane ----------------

__device__ __forceinline__ void acc_row16(const __half* __restrict__ base, float* a) {
    uint4 raw = *reinterpret_cast<const uint4*>(base);
    float2 f0 = __half22float2(*reinterpret_cast<const __half2*>(&raw.x));
    float2 f1 = __half22float2(*reinterpret_cast<const __half2*>(&raw.y));
    float2 f2 = __half22float2(*reinterpret_cast<const __half2*>(&raw.z));
    float2 f3 = __half22float2(*reinterpret_cast<const __half2*>(&raw.w));
    a[0] += f0.x; a[1] += f0.y; a[2] += f1.x; a[3] += f1.y;
    a[4] += f2.x; a[5] += f2.y; a[6] += f3.x; a[7] += f3.y;
}

// ---------------- Aggregation layer 1: wave per node ----------------
// 64 lanes = 8 edge-groups x 8 lanes; each lane loads 16B -> one dwordx4 per
// group covers the full 64-feature row; wave does 8 edges per load round.

__global__ __launch_bounds__(256) void agg1_kernel(const __half* __restrict__ g1,
                                                   const int* __restrict__ tmpB,
                                                   const int* __restrict__ bscanB,
                                                   const int* __restrict__ deg,
                                                   const int* __restrict__ csr,
                                                   const float* __restrict__ dinv,
                                                   const float* __restrict__ b1,
                                                   __half* __restrict__ h1, int n) {
    int node = (blockIdx.x * 256 + threadIdx.x) >> 6;
    int lane = threadIdx.x & 63;
    int g = lane >> 3;        // edge group 0..7
    int f8 = lane & 7;        // 16B feature chunk 0..7
    if (node >= n) return;
    int start = tmpB[node] + bscanB[node >> 10];
    int end = start + deg[node];
    float a[8];
#pragma unroll
    for (int j = 0; j < 8; ++j) a[j] = 0.f;
    if (g == 0)  // self loop counted once
        acc_row16(g1 + ((size_t)node << 6) + f8 * 8, a);
    int e = start;
    for (; e + 16 <= end; e += 16) {
        int s0 = csr[e + g];
        int s1 = csr[e + 8 + g];
        acc_row16(g1 + ((size_t)s0 << 6) + f8 * 8, a);
        acc_row16(g1 + ((size_t)s1 << 6) + f8 * 8, a);
    }
    for (; e + 8 <= end; e += 8) {
        int s = csr[e + g];
        acc_row16(g1 + ((size_t)s << 6) + f8 * 8, a);
    }
    if (e + g < end) {
        int s = csr[e + g];
        acc_row16(g1 + ((size_t)s << 6) + f8 * 8, a);
    }
    // fold 8 edge groups (chunk f8 lives in lanes f8 + 8*g)
#pragma unroll
    for (int j = 0; j < 8; ++j) a[j] += __shfl_xor(a[j], 8);
#pragma unroll
    for (int j = 0; j < 8; ++j) a[j] += __shfl_xor(a[j], 16);
#pragma unroll
    for (int j = 0; j < 8; ++j) a[j] += __shfl_xor(a[j], 32);
    if (g == 0) {
        float dn = dinv[node];
        float4 bl = *reinterpret_cast<const float4*>(b1 + f8 * 8);
        float4 bh = *reinterpret_cast<const float4*>(b1 + f8 * 8 + 4);
        __half hh[8];
        hh[0] = __float2half(fmaxf(a[0] * dn + bl.x, 0.f));
        hh[1] = __float2half(fmaxf(a[1] * dn + bl.y, 0.f));
        hh[2] = __float2half(fmaxf(a[2] * dn + bl.z, 0.f));
        hh[3] = __float2half(fmaxf(a[3] * dn + bl.w, 0.f));
        hh[4] = __float2half(fmaxf(a[4] * dn + bh.x, 0.f));
        hh[5] = __float2half(fmaxf(a[5] * dn + bh.y, 0.f));
        hh[6] = __float2half(fmaxf(a[6] * dn + bh.z, 0.f));
        hh[7] = __float2half(fmaxf(a[7] * dn + bh.w, 0.f));
        *reinterpret_cast<uint4*>(h1 + ((size_t)node << 6) + f8 * 8) =
            *reinterpret_cast<const uint4*>(hh);
    }
}

// ---------------- Aggregation layer 2 + pooling: wave per node ----------------
// 64 lanes = 16 edge-groups x 4 lanes (32-feat row = 4 x 16B). 16 edges/round.

__global__ __launch_bounds__(256) void agg2_pool_kernel(const __half* __restrict__ g2,
                                                        const int* __restrict__ tmpB,
                                                        const int* __restrict__ bscanB,
                                                        const int* __restrict__ deg,
                                                        const int* __restrict__ csr,
                                                        const float* __restrict__ dinv,
                                                        const float* __restrict__ b2,
                                                        float* __restrict__ partials,
                                                        int nblocks, int n) {
    int node = (blockIdx.x * 256 + threadIdx.x) >> 6;
    int w = (threadIdx.x >> 6) & 3;  // wave in block
    int lane = threadIdx.x & 63;
    int g = lane >> 2;       // edge group 0..15
    int f4 = lane & 3;       // 16B feature chunk 0..3
    float a[8];
#pragma unroll
    for (int j = 0; j < 8; ++j) a[j] = 0.f;
    if (node < n) {
        int start = tmpB[node] + bscanB[node >> 10];
        int end = start + deg[node];
        if (g == 0)
            acc_row16(g2 + ((size_t)node << 5) + f4 * 8, a);
        int e = start;
        for (; e + 16 <= end; e += 16) {
            int s = csr[e + g];
            acc_row16(g2 + ((size_t)s << 5) + f4 * 8, a);
        }
        if (e + g < end) {
            int s = csr[e + g];
            acc_row16(g2 + ((size_t)s << 5) + f4 * 8, a);
        }
#pragma unroll
        for (int j = 0; j < 8; ++j) a[j] += __shfl_xor(a[j], 4);
#pragma unroll
        for (int j = 0; j < 8; ++j) a[j] += __shfl_xor(a[j], 8);
#pragma unroll
        for (int j = 0; j < 8; ++j) a[j] += __shfl_xor(a[j], 16);
#pragma unroll
        for (int j = 0; j < 8; ++j) a[j] += __shfl_xor(a[j], 32);
    }
    __shared__ float sdata[4][32];
    if (g == 0) {
        float relu[8];
        if (node < n) {
            float dn = dinv[node];
#pragma unroll
            for (int j = 0; j < 8; ++j)
                relu[j] = fmaxf(a[j] * dn + b2[f4 * 8 + j], 0.f);
        } else {
#pragma unroll
            for (int j = 0; j < 8; ++j) relu[j] = 0.f;
        }
#pragma unroll
        for (int j = 0; j < 8; ++j) sdata[w][f4 * 8 + j] = relu[j];
    }
    __syncthreads();
    if (threadIdx.x < 32) {
        float s = sdata[0][threadIdx.x] + sdata[1][threadIdx.x] +
                  sdata[2][threadIdx.x] + sdata[3][threadIdx.x];
        partials[threadIdx.x * nblocks + blockIdx.x] = s;
    }
}

// 32 blocks, one per feature; fused FC: atomicAdd into pre-zeroed out[0].
__global__ __launch_bounds__(256) void reduce_fc_kernel(const float* __restrict__ partials,
                                                        int nblocks,
                                                        const float* __restrict__ fcw,
                                                        const float* __restrict__ fcb,
                                                        float* __restrict__ out, int n) {
    int f = blockIdx.x;
    const float* col = partials + (size_t)f * nblocks;
    float s = 0.f;
    for (int i = threadIdx.x; i < nblocks; i += 256) s += col[i];
    __shared__ float red[256];
    red[threadIdx.x] = s;
    __syncthreads();
    for (int ofs = 128; ofs > 0; ofs >>= 1) {
        if (threadIdx.x < ofs) red[threadIdx.x] += red[threadIdx.x + ofs];
        __syncthreads();
    }
    if (threadIdx.x == 0) {
        float v = (float)((double)red[0] / (double)n * (double)fcw[f]);
        if (f == 0) v += fcb[0];
        atomicAdd(out, v);
    }
}

// ---------------- launch ----------------

extern "C" void kernel_launch(void* const* d_in, const int* in_sizes, int n_in,
                              void* d_out, int out_size, void* d_ws, size_t ws_size,
                              hipStream_t stream) {
    const float* x   = (const float*)d_in[0];
    const int*   ei  = (const int*)d_in[1];
    const float* W1  = (const float*)d_in[2];
    const float* b1  = (const float*)d_in[3];
    const float* W2  = (const float*)d_in[4];
    const float* b2  = (const float*)d_in[5];
    const float* fcw = (const float*)d_in[6];
    const float* fcb = (const float*)d_in[7];
    float* out = (float*)d_out;

    const int N = in_sizes[0] / 256;  // 100000
    const int E = in_sizes[1] / 2;    // 3200000
    const int* src = ei;
    const int* dst = ei + E;

    const int NB = (N + BNODES - 1) >> BSH;           // 782 buckets
    const int SC = NB * NBLK;                         // hist entries
    const int CH = (((E + NBLK - 1) / NBLK) + 3) & ~3; // edges/block, x4 aligned
    const int nb2 = (N + 3) / 4;                      // agg2 blocks

    char* ws = (char*)d_ws;
    size_t off = 0;
    auto alloc = [&](size_t bytes) -> void* {
        void* p = ws + off;
        off = (off + bytes + 255) & ~(size_t)255;
        return p;
    };
    int*   tmp      = (int*)alloc((size_t)SC * 4);   // scan1 (bucket offsets)
    int*   bsums    = (int*)alloc(2048);
    int*   bscan    = (int*)alloc(2048);
    int*   tmpB     = (int*)alloc((size_t)N * 4);    // scan2 (row offsets)
    int*   bsumsB   = (int*)alloc(2048);
    int*   bscanB   = (int*)alloc(2048);
    int*   deg      = (int*)alloc((size_t)N * 4);
    float* dinv     = (float*)alloc((size_t)N * 4);
    int*   csr      = (int*)alloc((size_t)E * 4);
    __half* W1t     = (__half*)alloc((size_t)64 * 256 * 2);
    __half* W2t     = (__half*)alloc((size_t)32 * 64 * 2);
    // region P: buck (E int) aliases g1 (N*F1 halves) — buck dead before gemm1
    size_t szP = (size_t)E * 4;
    size_t szG1 = (size_t)N * F1 * 2;
    void* P = alloc(szP > szG1 ? szP : szG1);
    int*    buck = (int*)P;
    __half* g1   = (__half*)P;
    // region Q: hist_T aliases h1 — hist dead after scan1
    size_t szH = (size_t)SC * 4;
    size_t szH1 = (size_t)N * F1 * 2;
    void* Q = alloc(szH > szH1 ? szH : szH1);
    int* hist_T = (int*)Q;
    __half* h1  = (__half*)Q;
    __half* g2      = (__half*)alloc((size_t)N * F2 * 2);
    float* partials = (float*)alloc((size_t)F2 * nb2 * 4);

    hipMemsetAsync(out, 0, sizeof(float), stream);

    // ---- CSR build via counting sort + weight prep ----
    bucket_hist_prep_kernel<<<NBLK + 1, 256, 0, stream>>>(dst, hist_T, W1, W2, W1t, W2t, E, CH, NB);
    int nbS = (SC + 1023) / 1024;  // 391
    scan_blocks_kernel<<<nbS, 256, 0, stream>>>(hist_T, tmp, bsums, SC);
    scan_sums_kernel<<<1, 512, 0, stream>>>(bsums, bscan, nbS);
    bucket_scatter_kernel<<<NBLK, 256, 0, stream>>>(src, dst, tmp, bscan, buck, E, CH, NB);
    bucket_deg_kernel<<<NB, 256, 0, stream>>>(buck, tmp, bscan, deg, dinv, E, N, NB);
    int nbS2 = (N + 1023) / 1024;  // 98
    scan_blocks_kernel<<<nbS2, 256, 0, stream>>>(deg, tmpB, bsumsB, N);
    scan_sums_kernel<<<1, 512, 0, stream>>>(bsumsB, bscanB, nbS2);
    bucket_fill_kernel<<<NB, 256, 0, stream>>>(buck, tmp, bscan, tmpB, bscanB, csr, E, N, NB);

    int nbG = (N + 63) / 64;  // 1563
    // ---- layer 1 ----
    gemm_mfma_kernel<true, 256, 64><<<nbG, 256, 0, stream>>>(x, W1t, dinv, g1, N);
    agg1_kernel<<<(N + 3) / 4, 256, 0, stream>>>(g1, tmpB, bscanB, deg, csr, dinv, b1, h1, N);

    // ---- layer 2 ----
    gemm_mfma_kernel<false, 64, 32><<<nbG, 256, 0, stream>>>(h1, W2t, dinv, g2, N);
    agg2_pool_kernel<<<nb2, 256, 0, stream>>>(g2, tmpB, bscanB, deg, csr, dinv, b2, partials, nb2, N);

    reduce_fc_kernel<<<F2, 256, 0, stream>>>(partials, nb2, fcw, fcb, out, N);
}